// Round 15
// baseline (256.187 us; speedup 1.0000x reference)
//
#include <hip/hip_runtime.h>
#include <hip/hip_fp16.h>

#define DD 64
#define NB 256          // buckets (one per passC2 block); requires n <= 65536
#define GB 128          // blocks for histA/passB2

// ---------------------------------------------------------------------------
// Inline int64-vs-int32 detection: first 128 odd u32 words all zero <=> int64.
__device__ __forceinline__ int detect_is64(const unsigned int* p, int E,
                                           int tid, int* sflag) {
  if (tid == 0) *sflag = 1;
  __syncthreads();
  int lim = E < 128 ? E : 128;
  if (tid < lim && p[2 * tid + 1] != 0u) *sflag = 0;
  __syncthreads();
  return *sflag;
}

// ---- histA: per-(block,bucket) histogram of dst ---------------------------
__global__ __launch_bounds__(256) void histA_kernel(
    const void* __restrict__ eidx, int E, int chunk,
    int* __restrict__ histPB) {
  __shared__ int h[NB];
  __shared__ int sflag;
  int tid = threadIdx.x;
  int is64 = detect_is64((const unsigned int*)eidx, E, tid, &sflag);
  h[tid] = 0;
  __syncthreads();
  int seg = (E + GB - 1) / GB;
  int e0 = blockIdx.x * seg;
  int e1 = min(e0 + seg, E);
  for (int e = e0 + tid; e < e1; e += 256) {
    int d;
    if (is64) d = (int)((const long long*)eidx)[e + E];
    else      d = ((const int*)eidx)[e + E];
    atomicAdd(&h[d / chunk], 1);
  }
  __syncthreads();
  histPB[blockIdx.x * NB + tid] = h[tid];
}

// ---- passB2: recompute bases from histPB, then bucketed scatter -----------
__global__ __launch_bounds__(256) void passB2_kernel(
    const void* __restrict__ eidx, int E, int chunk,
    const int* __restrict__ histPB, unsigned int* __restrict__ rec) {
  __shared__ int cur[NB];
  __shared__ int sc[NB];
  __shared__ int sflag;
  int tid = threadIdx.x;
  int blk = blockIdx.x;
  int is64 = detect_is64((const unsigned int*)eidx, E, tid, &sflag);

  // bucket tid: total over all source blocks + prefix over blocks < blk
  int tot = 0, pre = 0;
  for (int t = 0; t < GB; ++t) {
    int v = histPB[t * NB + tid];
    tot += v;
    if (t < blk) pre += v;
  }
  sc[tid] = tot;
  __syncthreads();
  for (int off = 1; off < NB; off <<= 1) {
    int t = (tid >= off) ? sc[tid - off] : 0;
    __syncthreads();
    sc[tid] += t;
    __syncthreads();
  }
  cur[tid] = (sc[tid] - tot) + pre;   // bucketBase + local prefix
  __syncthreads();

  int seg = (E + GB - 1) / GB;
  int e0 = blk * seg;
  int e1 = min(e0 + seg, E);
  for (int e = e0 + tid; e < e1; e += 256) {
    int s, d;
    if (is64) {
      const long long* p = (const long long*)eidx;
      s = (int)p[e];
      d = (int)p[e + E];
    } else {
      const int* p = (const int*)eidx;
      s = p[e];
      d = p[e + E];
    }
    int b = d / chunk;
    int ld = d - b * chunk;
    int pos = atomicAdd(&cur[b], 1);
    rec[pos] = ((unsigned int)s << 16) | (unsigned int)ld;
  }
}

// ---- passC2: recompute bases, then per-bucket CSR finalize ----------------
__global__ __launch_bounds__(256) void passC2_kernel(
    const unsigned int* __restrict__ rec, const int* __restrict__ histPB,
    int* __restrict__ offs, float* __restrict__ dinv, int* __restrict__ col,
    int n, int E, int chunk) {
  int b = blockIdx.x;
  int tid = threadIdx.x;
  __shared__ int sc[NB];
  __shared__ int hist[NB];
  __shared__ int cursor[NB];
  __shared__ int jb0s, jb1s;

  // recompute bucket totals + scan -> this bucket's record range
  int tot = 0;
  for (int t = 0; t < GB; ++t) tot += histPB[t * NB + tid];
  sc[tid] = tot;
  __syncthreads();
  for (int off = 1; off < NB; off <<= 1) {
    int t = (tid >= off) ? sc[tid - off] : 0;
    __syncthreads();
    sc[tid] += t;
    __syncthreads();
  }
  if (tid == b) { jb0s = sc[tid] - tot; jb1s = sc[tid]; }
  __syncthreads();
  int jb0 = jb0s, jb1 = jb1s;

  if (b == 0 && tid == 0) offs[n] = E + n;
  int d0 = b * chunk;
  if (d0 >= n) return;
  int nd = min(chunk, n - d0);
  int cb = jb0 + d0;                 // csrBase (d0 < n here)

  hist[tid] = (tid < nd) ? 1 : 0;    // self-loop seed
  __syncthreads();
  for (int j = jb0 + tid; j < jb1; j += 256)
    atomicAdd(&hist[rec[j] & 0xFFFFu], 1);
  __syncthreads();
  int deg = hist[tid];
  sc[tid] = deg;
  __syncthreads();
  for (int off = 1; off < NB; off <<= 1) {
    int t = (tid >= off) ? sc[tid - off] : 0;
    __syncthreads();
    sc[tid] += t;
    __syncthreads();
  }
  int loc = sc[tid] - deg;           // exclusive prefix
  if (tid < nd) {
    offs[d0 + tid] = cb + loc;
    dinv[d0 + tid] = rsqrtf((float)deg);
    col[cb + loc] = d0 + tid;        // self-loop first
  }
  cursor[tid] = loc + 1;
  __syncthreads();
  for (int j = jb0 + tid; j < jb1; j += 256) {
    unsigned int r = rec[j];
    int p = atomicAdd(&cursor[(int)(r & 0xFFFFu)], 1);
    col[cb + p] = (int)(r >> 16);
  }
}

// ---- fused layer0 + transform1: T16 = dinv * (relu(x@Win + bin) @ W1) -----
// 32-row tile, 256 threads (thread = 1 row x 8 cols), 26 KB LDS.
__global__ __launch_bounds__(256) void gemm01_kernel(
    const float* __restrict__ X, const float* __restrict__ Win,
    const float* __restrict__ bin, const float* __restrict__ W1,
    const float* __restrict__ dinv, __half* __restrict__ T16, int n) {
  __shared__ float Ws[64][68];
  __shared__ float Hs[32][68];
  int tid = threadIdx.x;
  int row0 = blockIdx.x * 32;

  for (int i = tid; i < 1024; i += 256) {
    int r = i >> 4, c = (i & 15) << 2;
    *reinterpret_cast<float4*>(&Ws[r][c]) = ((const float4*)Win)[i];
  }
  for (int i = tid; i < 512; i += 256) {
    int r = i >> 4, c = (i & 15) << 2;
    float4 hv = make_float4(0.f, 0.f, 0.f, 0.f);
    if (row0 + r < n)
      hv = *reinterpret_cast<const float4*>(X + (size_t)(row0 + r) * DD + c);
    *reinterpret_cast<float4*>(&Hs[r][c]) = hv;
  }
  __syncthreads();

  int r = tid >> 3;          // 0..31
  int c0 = (tid & 7) << 3;   // cols c0..c0+7

  float acc[8];
#pragma unroll
  for (int j = 0; j < 8; ++j) acc[j] = 0.f;
#pragma unroll
  for (int k = 0; k < 64; ++k) {
    float hv = Hs[r][k];
    float4 w0 = *reinterpret_cast<const float4*>(&Ws[k][c0]);
    float4 w1 = *reinterpret_cast<const float4*>(&Ws[k][c0 + 4]);
    acc[0] = fmaf(hv, w0.x, acc[0]); acc[1] = fmaf(hv, w0.y, acc[1]);
    acc[2] = fmaf(hv, w0.z, acc[2]); acc[3] = fmaf(hv, w0.w, acc[3]);
    acc[4] = fmaf(hv, w1.x, acc[4]); acc[5] = fmaf(hv, w1.y, acc[5]);
    acc[6] = fmaf(hv, w1.z, acc[6]); acc[7] = fmaf(hv, w1.w, acc[7]);
  }
  // h = relu(acc + bin)
  float4 b0 = *reinterpret_cast<const float4*>(bin + c0);
  float4 b1v = *reinterpret_cast<const float4*>(bin + c0 + 4);
  float h[8];
  h[0] = fmaxf(acc[0] + b0.x, 0.f);  h[1] = fmaxf(acc[1] + b0.y, 0.f);
  h[2] = fmaxf(acc[2] + b0.z, 0.f);  h[3] = fmaxf(acc[3] + b0.w, 0.f);
  h[4] = fmaxf(acc[4] + b1v.x, 0.f); h[5] = fmaxf(acc[5] + b1v.y, 0.f);
  h[6] = fmaxf(acc[6] + b1v.z, 0.f); h[7] = fmaxf(acc[7] + b1v.w, 0.f);
  __syncthreads();           // everyone done reading Hs/Ws

  *reinterpret_cast<float4*>(&Hs[r][c0])     = make_float4(h[0], h[1], h[2], h[3]);
  *reinterpret_cast<float4*>(&Hs[r][c0 + 4]) = make_float4(h[4], h[5], h[6], h[7]);
  for (int i = tid; i < 1024; i += 256) {
    int rr = i >> 4, c = (i & 15) << 2;
    *reinterpret_cast<float4*>(&Ws[rr][c]) = ((const float4*)W1)[i];
  }
  __syncthreads();

#pragma unroll
  for (int j = 0; j < 8; ++j) acc[j] = 0.f;
#pragma unroll
  for (int k = 0; k < 64; ++k) {
    float hv = Hs[r][k];
    float4 w0 = *reinterpret_cast<const float4*>(&Ws[k][c0]);
    float4 w1 = *reinterpret_cast<const float4*>(&Ws[k][c0 + 4]);
    acc[0] = fmaf(hv, w0.x, acc[0]); acc[1] = fmaf(hv, w0.y, acc[1]);
    acc[2] = fmaf(hv, w0.z, acc[2]); acc[3] = fmaf(hv, w0.w, acc[3]);
    acc[4] = fmaf(hv, w1.x, acc[4]); acc[5] = fmaf(hv, w1.y, acc[5]);
    acc[6] = fmaf(hv, w1.z, acc[6]); acc[7] = fmaf(hv, w1.w, acc[7]);
  }
  long long row = (long long)row0 + r;
  if (row < n) {
    float dv = dinv[row];
    __half2 p01 = __floats2half2_rn(acc[0] * dv, acc[1] * dv);
    __half2 p23 = __floats2half2_rn(acc[2] * dv, acc[3] * dv);
    __half2 p45 = __floats2half2_rn(acc[4] * dv, acc[5] * dv);
    __half2 p67 = __floats2half2_rn(acc[6] * dv, acc[7] * dv);
    uint4 u;
    u.x = *reinterpret_cast<unsigned int*>(&p01);
    u.y = *reinterpret_cast<unsigned int*>(&p23);
    u.z = *reinterpret_cast<unsigned int*>(&p45);
    u.w = *reinterpret_cast<unsigned int*>(&p67);
    *reinterpret_cast<uint4*>(T16 + (size_t)row * DD + c0) = u;
  }
}

// ---- shared gather core ---------------------------------------------------
__device__ __forceinline__ void acc8(float* acc, uint4 u) {
  __half2 h0 = *reinterpret_cast<__half2*>(&u.x);
  __half2 h1 = *reinterpret_cast<__half2*>(&u.y);
  __half2 h2 = *reinterpret_cast<__half2*>(&u.z);
  __half2 h3 = *reinterpret_cast<__half2*>(&u.w);
  float2 f0 = __half22float2(h0);
  float2 f1 = __half22float2(h1);
  float2 f2 = __half22float2(h2);
  float2 f3 = __half22float2(h3);
  acc[0] += f0.x; acc[1] += f0.y;
  acc[2] += f1.x; acc[3] += f1.y;
  acc[4] += f2.x; acc[5] += f2.y;
  acc[6] += f3.x; acc[7] += f3.y;
}

// gather neighbor-sum for node wid into acc[8] (slice s, group g);
// after the butterfly, ALL lanes hold the full sum of dims 8s..8s+7.
__device__ __forceinline__ void gather_node(
    const __half* __restrict__ Ts, const int* __restrict__ col,
    int j0, int deg, int lane, int g, float* acc) {
#pragma unroll
  for (int k = 0; k < 8; ++k) acc[k] = 0.f;
  for (int base = 0; base < deg; base += 64) {
    int idx = base + lane;
    int c_local = (idx < deg) ? col[j0 + idx] : -1;
    int rem = deg - base; if (rem > 64) rem = 64;
    int nr = (rem + 7) >> 3;

    int cc[8];
#pragma unroll
    for (int t = 0; t < 8; ++t)
      cc[t] = (t < nr) ? __shfl(c_local, t * 8 + g, 64) : -1;

    uint4 u[8];
#pragma unroll
    for (int t = 0; t < 8; ++t)
      if (cc[t] >= 0)
        u[t] = *reinterpret_cast<const uint4*>(Ts + (size_t)cc[t] * DD);

#pragma unroll
    for (int t = 0; t < 8; ++t)
      if (cc[t] >= 0) acc8(acc, u[t]);
  }
#pragma unroll
  for (int m = 8; m <= 32; m <<= 1) {
#pragma unroll
    for (int k = 0; k < 8; ++k)
      acc[k] += __shfl_xor(acc[k], m, 64);
  }
}

// ---- fused aggregate + next transform (per-node, no cross-block coupling) -
// Tout[node,:] = dinv[node] * (relu(dinv[node]*agg(Tin)[node] + b) @ Wn)
__global__ __launch_bounds__(256) void aggT_kernel(
    const __half* __restrict__ Tin, const int* __restrict__ offs,
    const int* __restrict__ col, const float* __restrict__ dinv,
    const float* __restrict__ bias, const float* __restrict__ Wn,
    __half* __restrict__ Tout, int n) {
  __shared__ __half WsH[64][64];     // 8 KB, fp16 W
  int tid = threadIdx.x;
  for (int i = tid; i < 1024; i += 256) {
    float4 wv = ((const float4*)Wn)[i];
    int r = i >> 4, c = (i & 15) << 2;
    __half2 a = __floats2half2_rn(wv.x, wv.y);
    __half2 b = __floats2half2_rn(wv.z, wv.w);
    *reinterpret_cast<__half2*>(&WsH[r][c])     = a;
    *reinterpret_cast<__half2*>(&WsH[r][c + 2]) = b;
  }
  __syncthreads();

  int gid = blockIdx.x * blockDim.x + tid;
  int wid = gid >> 6;
  if (wid >= n) return;
  int lane = tid & 63;
  int g = lane >> 3, s = lane & 7;
  int j0 = offs[wid], j1 = offs[wid + 1];

  float acc[8];
  gather_node(Tin + s * 8, col, j0, j1 - j0, lane, g, acc);

  float dv = dinv[wid];
  const float4* bp = reinterpret_cast<const float4*>(bias + s * 8);
  float4 b0 = bp[0], b1v = bp[1];
  float q[8];
  q[0] = fmaxf(fmaf(acc[0], dv, b0.x), 0.f);
  q[1] = fmaxf(fmaf(acc[1], dv, b0.y), 0.f);
  q[2] = fmaxf(fmaf(acc[2], dv, b0.z), 0.f);
  q[3] = fmaxf(fmaf(acc[3], dv, b0.w), 0.f);
  q[4] = fmaxf(fmaf(acc[4], dv, b1v.x), 0.f);
  q[5] = fmaxf(fmaf(acc[5], dv, b1v.y), 0.f);
  q[6] = fmaxf(fmaf(acc[6], dv, b1v.z), 0.f);
  q[7] = fmaxf(fmaf(acc[7], dv, b1v.w), 0.f);

  // lane computes output column `lane`: o = sum_k q_full[k] * W[k][lane]
  float o = 0.f;
#pragma unroll
  for (int c = 0; c < 8; ++c) {
    int src = (lane & 56) | c;       // same g, s = c -> holds q[8c..8c+7]
#pragma unroll
    for (int j = 0; j < 8; ++j) {
      float qv = __shfl(q[j], src, 64);
      o = fmaf(qv, __half2float(WsH[8 * c + j][lane]), o);
    }
  }
  Tout[(size_t)wid * DD + lane] = __float2half_rn(o * dv);
}

// ---- final CSR aggregation: out = dinv*agg(T) + b (fp32, no relu) ---------
__global__ __launch_bounds__(256) void aggregate_kernel(
    const __half* __restrict__ T, const int* __restrict__ offs,
    const int* __restrict__ col, const float* __restrict__ dinv,
    const float* __restrict__ bias, float* __restrict__ out, int n) {
  int gid = blockIdx.x * blockDim.x + threadIdx.x;
  int wid = gid >> 6;
  if (wid >= n) return;
  int lane = threadIdx.x & 63;
  int g = lane >> 3, s = lane & 7;
  int j0 = offs[wid], j1 = offs[wid + 1];
  float acc[8];
  gather_node(T + s * 8, col, j0, j1 - j0, lane, g, acc);

  if (g == 0) {
    float dv = dinv[wid];
    const float4* bp = reinterpret_cast<const float4*>(bias + s * 8);
    float4 b0 = bp[0], b1 = bp[1];
    float4 o0, o1;
    o0.x = fmaf(acc[0], dv, b0.x);
    o0.y = fmaf(acc[1], dv, b0.y);
    o0.z = fmaf(acc[2], dv, b0.z);
    o0.w = fmaf(acc[3], dv, b0.w);
    o1.x = fmaf(acc[4], dv, b1.x);
    o1.y = fmaf(acc[5], dv, b1.y);
    o1.z = fmaf(acc[6], dv, b1.z);
    o1.w = fmaf(acc[7], dv, b1.w);
    float4* op = reinterpret_cast<float4*>(out + (size_t)wid * DD + s * 8);
    op[0] = o0;
    op[1] = o1;
  }
}

// ---------------------------------------------------------------------------
extern "C" void kernel_launch(void* const* d_in, const int* in_sizes, int n_in,
                              void* d_out, int out_size, void* d_ws, size_t ws_size,
                              hipStream_t stream) {
  const float* x   = (const float*)d_in[0];
  const void*  eix = d_in[1];
  const float* Win = (const float*)d_in[2];
  const float* bin = (const float*)d_in[3];
  const float* W1  = (const float*)d_in[4];
  const float* b1  = (const float*)d_in[5];
  const float* W2  = (const float*)d_in[6];
  const float* b2  = (const float*)d_in[7];
  const float* W3  = (const float*)d_in[8];
  const float* b3  = (const float*)d_in[9];

  int n = in_sizes[0] / DD;
  int E = in_sizes[1] / 2;
  int M = E + n;
  int chunk = (n + NB - 1) / NB;    // local-dst fits 16 bits for n <= 65536

  char* w = (char*)d_ws;
  auto carve = [&](size_t bytes) {
    char* p = w;
    w += (bytes + 255) & ~(size_t)255;
    return p;
  };
  int*          histPB = (int*)carve((size_t)GB * NB * 4);
  int*          offs   = (int*)carve((size_t)(n + 1) * 4);
  float*        dinv   = (float*)carve((size_t)n * 4);
  unsigned int* rec    = (unsigned int*)carve((size_t)E * 4);
  int*          col    = (int*)carve((size_t)M * 4);
  __half*       t16a   = (__half*)carve((size_t)n * DD * 2);
  __half*       t16b   = (__half*)carve((size_t)n * DD * 2);

  histA_kernel<<<GB, 256, 0, stream>>>(eix, E, chunk, histPB);
  passB2_kernel<<<GB, 256, 0, stream>>>(eix, E, chunk, histPB, rec);
  passC2_kernel<<<NB, 256, 0, stream>>>(rec, histPB, offs, dinv, col, n, E, chunk);

  int g01_grid = (n + 31) / 32;
  int agg_grid = (n * 64 + 255) / 256;

  // t16a = dinv * (relu(x@Win+bin) @ W1)
  gemm01_kernel<<<g01_grid, 256, 0, stream>>>(x, Win, bin, W1, dinv, t16a, n);
  // conv1 + transform2: t16b = dinv * (relu(dinv*agg(t16a)+b1) @ W2)
  aggT_kernel<<<agg_grid, 256, 0, stream>>>(t16a, offs, col, dinv, b1, W2, t16b, n);
  // conv2 + transform3: t16a = dinv * (relu(dinv*agg(t16b)+b2) @ W3)
  aggT_kernel<<<agg_grid, 256, 0, stream>>>(t16b, offs, col, dinv, b2, W3, t16a, n);
  // conv3: out = dinv*agg(t16a) + b3
  aggregate_kernel<<<agg_grid, 256, 0, stream>>>(t16a, offs, col, dinv, b3, (float*)d_out, n);
}

// Round 16
// 221.192 us; speedup vs baseline: 1.1582x; 1.1582x over previous
//
#include <hip/hip_runtime.h>
#include <hip/hip_fp16.h>

#define DD 64
#define NB 256          // buckets (one per passC2 block); requires n <= 65536
#define GB 128          // blocks for histA/passB2

// ---------------------------------------------------------------------------
// Inline int64-vs-int32 detection: first 128 odd u32 words all zero <=> int64.
__device__ __forceinline__ int detect_is64(const unsigned int* p, int E,
                                           int tid, int* sflag) {
  if (tid == 0) *sflag = 1;
  __syncthreads();
  int lim = E < 128 ? E : 128;
  if (tid < lim && p[2 * tid + 1] != 0u) *sflag = 0;
  __syncthreads();
  return *sflag;
}

// ---- histA: per-(block,bucket) histogram of dst ---------------------------
__global__ __launch_bounds__(256) void histA_kernel(
    const void* __restrict__ eidx, int E, int chunk,
    int* __restrict__ histPB) {
  __shared__ int h[NB];
  __shared__ int sflag;
  int tid = threadIdx.x;
  int is64 = detect_is64((const unsigned int*)eidx, E, tid, &sflag);
  h[tid] = 0;
  __syncthreads();
  int seg = (E + GB - 1) / GB;
  int e0 = blockIdx.x * seg;
  int e1 = min(e0 + seg, E);
  for (int e = e0 + tid; e < e1; e += 256) {
    int d;
    if (is64) d = (int)((const long long*)eidx)[e + E];
    else      d = ((const int*)eidx)[e + E];
    atomicAdd(&h[d / chunk], 1);
  }
  __syncthreads();
  histPB[blockIdx.x * NB + tid] = h[tid];
}

// ---- passB2: recompute bases from histPB, then bucketed scatter -----------
__global__ __launch_bounds__(256) void passB2_kernel(
    const void* __restrict__ eidx, int E, int chunk,
    const int* __restrict__ histPB, unsigned int* __restrict__ rec) {
  __shared__ int cur[NB];
  __shared__ int sc[NB];
  __shared__ int sflag;
  int tid = threadIdx.x;
  int blk = blockIdx.x;
  int is64 = detect_is64((const unsigned int*)eidx, E, tid, &sflag);

  // bucket tid: total over all source blocks + prefix over blocks < blk
  int tot = 0, pre = 0;
  for (int t = 0; t < GB; ++t) {
    int v = histPB[t * NB + tid];
    tot += v;
    if (t < blk) pre += v;
  }
  sc[tid] = tot;
  __syncthreads();
  for (int off = 1; off < NB; off <<= 1) {
    int t = (tid >= off) ? sc[tid - off] : 0;
    __syncthreads();
    sc[tid] += t;
    __syncthreads();
  }
  cur[tid] = (sc[tid] - tot) + pre;   // bucketBase + local prefix
  __syncthreads();

  int seg = (E + GB - 1) / GB;
  int e0 = blk * seg;
  int e1 = min(e0 + seg, E);
  for (int e = e0 + tid; e < e1; e += 256) {
    int s, d;
    if (is64) {
      const long long* p = (const long long*)eidx;
      s = (int)p[e];
      d = (int)p[e + E];
    } else {
      const int* p = (const int*)eidx;
      s = p[e];
      d = p[e + E];
    }
    int b = d / chunk;
    int ld = d - b * chunk;
    int pos = atomicAdd(&cur[b], 1);
    rec[pos] = ((unsigned int)s << 16) | (unsigned int)ld;
  }
}

// ---- fused passC2 + gemm0 -------------------------------------------------
// blocks 0..NB-1   : per-bucket CSR finalize (offs, dinv, col)
// blocks NB..      : layer-0 GEMM tile: hbuf = relu(x @ Win + bin)  (fp32)
// The two halves are data-independent; merged to overlap on different CUs.
__global__ __launch_bounds__(256) void passC2_gemm0_kernel(
    const unsigned int* __restrict__ rec, const int* __restrict__ histPB,
    int* __restrict__ offs, float* __restrict__ dinv, int* __restrict__ col,
    int n, int E, int chunk,
    const float* __restrict__ X, const float* __restrict__ Win,
    const float* __restrict__ bin, float* __restrict__ hbuf) {
  __shared__ float smem[2 * 64 * 68];   // 34816 B, reused by both paths
  int tid = threadIdx.x;

  if (blockIdx.x < NB) {
    // ----- passC2 path -----
    int b = blockIdx.x;
    int* sc     = (int*)smem;
    int* hist   = sc + NB;
    int* cursor = hist + NB;
    __shared__ int jb0s, jb1s;

    int tot = 0;
    for (int t = 0; t < GB; ++t) tot += histPB[t * NB + tid];
    sc[tid] = tot;
    __syncthreads();
    for (int off = 1; off < NB; off <<= 1) {
      int t = (tid >= off) ? sc[tid - off] : 0;
      __syncthreads();
      sc[tid] += t;
      __syncthreads();
    }
    if (tid == b) { jb0s = sc[tid] - tot; jb1s = sc[tid]; }
    __syncthreads();
    int jb0 = jb0s, jb1 = jb1s;

    if (b == 0 && tid == 0) offs[n] = E + n;
    int d0 = b * chunk;
    if (d0 >= n) return;
    int nd = min(chunk, n - d0);
    int cb = jb0 + d0;                 // csrBase (d0 < n here)

    hist[tid] = (tid < nd) ? 1 : 0;    // self-loop seed
    __syncthreads();
    for (int j = jb0 + tid; j < jb1; j += 256)
      atomicAdd(&hist[rec[j] & 0xFFFFu], 1);
    __syncthreads();
    int deg = hist[tid];
    sc[tid] = deg;
    __syncthreads();
    for (int off = 1; off < NB; off <<= 1) {
      int t = (tid >= off) ? sc[tid - off] : 0;
      __syncthreads();
      sc[tid] += t;
      __syncthreads();
    }
    int loc = sc[tid] - deg;           // exclusive prefix
    if (tid < nd) {
      offs[d0 + tid] = cb + loc;
      dinv[d0 + tid] = rsqrtf((float)deg);
      col[cb + loc] = d0 + tid;        // self-loop first
    }
    cursor[tid] = loc + 1;
    __syncthreads();
    for (int j = jb0 + tid; j < jb1; j += 256) {
      unsigned int r = rec[j];
      int p = atomicAdd(&cursor[(int)(r & 0xFFFFu)], 1);
      col[cb + p] = (int)(r >> 16);
    }
  } else {
    // ----- gemm0 path: hbuf = relu(x @ Win + bin) -----
    float (*Ws)[68] = (float(*)[68])smem;
    float (*Hs)[68] = (float(*)[68])(smem + 64 * 68);
    int row0 = (blockIdx.x - NB) * 64;

    for (int i = tid; i < 1024; i += 256) {
      int r = i >> 4, c = (i & 15) << 2;
      *reinterpret_cast<float4*>(&Ws[r][c]) = ((const float4*)Win)[i];
      float4 hv = make_float4(0.f, 0.f, 0.f, 0.f);
      if (row0 + r < n)
        hv = *reinterpret_cast<const float4*>(X + (size_t)(row0 + r) * DD + c);
      *reinterpret_cast<float4*>(&Hs[r][c]) = hv;
    }
    __syncthreads();

    int tr = tid >> 4, tc = tid & 15;
    int r0 = tr << 2, c0 = tc << 2;

    float acc[4][4];
#pragma unroll
    for (int i = 0; i < 4; ++i)
#pragma unroll
      for (int j = 0; j < 4; ++j) acc[i][j] = 0.f;

#pragma unroll
    for (int k = 0; k < 64; ++k) {
      float h0 = Hs[r0 + 0][k], h1 = Hs[r0 + 1][k];
      float h2 = Hs[r0 + 2][k], h3 = Hs[r0 + 3][k];
      float4 wv = *reinterpret_cast<const float4*>(&Ws[k][c0]);
      acc[0][0] = fmaf(h0, wv.x, acc[0][0]); acc[0][1] = fmaf(h0, wv.y, acc[0][1]);
      acc[0][2] = fmaf(h0, wv.z, acc[0][2]); acc[0][3] = fmaf(h0, wv.w, acc[0][3]);
      acc[1][0] = fmaf(h1, wv.x, acc[1][0]); acc[1][1] = fmaf(h1, wv.y, acc[1][1]);
      acc[1][2] = fmaf(h1, wv.z, acc[1][2]); acc[1][3] = fmaf(h1, wv.w, acc[1][3]);
      acc[2][0] = fmaf(h2, wv.x, acc[2][0]); acc[2][1] = fmaf(h2, wv.y, acc[2][1]);
      acc[2][2] = fmaf(h2, wv.z, acc[2][2]); acc[2][3] = fmaf(h2, wv.w, acc[2][3]);
      acc[3][0] = fmaf(h3, wv.x, acc[3][0]); acc[3][1] = fmaf(h3, wv.y, acc[3][1]);
      acc[3][2] = fmaf(h3, wv.z, acc[3][2]); acc[3][3] = fmaf(h3, wv.w, acc[3][3]);
    }

    float4 bv = *reinterpret_cast<const float4*>(bin + c0);
#pragma unroll
    for (int i = 0; i < 4; ++i) {
      long long row = (long long)row0 + r0 + i;
      if (row >= n) break;
      float4 o;
      o.x = fmaxf(acc[i][0] + bv.x, 0.f);
      o.y = fmaxf(acc[i][1] + bv.y, 0.f);
      o.z = fmaxf(acc[i][2] + bv.z, 0.f);
      o.w = fmaxf(acc[i][3] + bv.w, 0.f);
      *reinterpret_cast<float4*>(hbuf + (size_t)row * DD + c0) = o;
    }
  }
}

// ---- dense GEMM: acc = H @ W; epilogue: bias+relu -> fp32, or dinv -> fp16 -
__global__ __launch_bounds__(256) void gemm_kernel(
    const float* __restrict__ H, const float* __restrict__ W,
    const float* __restrict__ bias, const float* __restrict__ dinv,
    float* __restrict__ T32, __half* __restrict__ T16, int n) {
  __shared__ float Ws[64][68];
  __shared__ float Hs[64][68];
  int tid = threadIdx.x;
  int row0 = blockIdx.x * 64;

  for (int i = tid; i < 1024; i += 256) {
    int r = i >> 4, c = (i & 15) << 2;
    *reinterpret_cast<float4*>(&Ws[r][c]) = ((const float4*)W)[i];
    float4 hv = make_float4(0.f, 0.f, 0.f, 0.f);
    if (row0 + r < n)
      hv = *reinterpret_cast<const float4*>(H + (size_t)(row0 + r) * DD + c);
    *reinterpret_cast<float4*>(&Hs[r][c]) = hv;
  }
  __syncthreads();

  int tr = tid >> 4, tc = tid & 15;
  int r0 = tr << 2, c0 = tc << 2;

  float acc[4][4];
#pragma unroll
  for (int i = 0; i < 4; ++i)
#pragma unroll
    for (int j = 0; j < 4; ++j) acc[i][j] = 0.f;

#pragma unroll
  for (int k = 0; k < 64; ++k) {
    float h0 = Hs[r0 + 0][k], h1 = Hs[r0 + 1][k];
    float h2 = Hs[r0 + 2][k], h3 = Hs[r0 + 3][k];
    float4 wv = *reinterpret_cast<const float4*>(&Ws[k][c0]);
    acc[0][0] = fmaf(h0, wv.x, acc[0][0]); acc[0][1] = fmaf(h0, wv.y, acc[0][1]);
    acc[0][2] = fmaf(h0, wv.z, acc[0][2]); acc[0][3] = fmaf(h0, wv.w, acc[0][3]);
    acc[1][0] = fmaf(h1, wv.x, acc[1][0]); acc[1][1] = fmaf(h1, wv.y, acc[1][1]);
    acc[1][2] = fmaf(h1, wv.z, acc[1][2]); acc[1][3] = fmaf(h1, wv.w, acc[1][3]);
    acc[2][0] = fmaf(h2, wv.x, acc[2][0]); acc[2][1] = fmaf(h2, wv.y, acc[2][1]);
    acc[2][2] = fmaf(h2, wv.z, acc[2][2]); acc[2][3] = fmaf(h2, wv.w, acc[2][3]);
    acc[3][0] = fmaf(h3, wv.x, acc[3][0]); acc[3][1] = fmaf(h3, wv.y, acc[3][1]);
    acc[3][2] = fmaf(h3, wv.z, acc[3][2]); acc[3][3] = fmaf(h3, wv.w, acc[3][3]);
  }

  if (T16) {
    // fp16 path: o = dinv[row] * acc
#pragma unroll
    for (int i = 0; i < 4; ++i) {
      long long row = (long long)row0 + r0 + i;
      if (row >= n) break;
      float dv = dinv[row];
      __half2 p01 = __floats2half2_rn(acc[i][0] * dv, acc[i][1] * dv);
      __half2 p23 = __floats2half2_rn(acc[i][2] * dv, acc[i][3] * dv);
      uint2 u;
      u.x = *reinterpret_cast<unsigned int*>(&p01);
      u.y = *reinterpret_cast<unsigned int*>(&p23);
      *reinterpret_cast<uint2*>(T16 + (size_t)row * DD + c0) = u;
    }
  } else {
    // fp32 path: o = relu(acc + bias)
    float4 bv = *reinterpret_cast<const float4*>(bias + c0);
#pragma unroll
    for (int i = 0; i < 4; ++i) {
      long long row = (long long)row0 + r0 + i;
      if (row >= n) break;
      float4 o;
      o.x = fmaxf(acc[i][0] + bv.x, 0.f);
      o.y = fmaxf(acc[i][1] + bv.y, 0.f);
      o.z = fmaxf(acc[i][2] + bv.z, 0.f);
      o.w = fmaxf(acc[i][3] + bv.w, 0.f);
      *reinterpret_cast<float4*>(T32 + (size_t)row * DD + c0) = o;
    }
  }
}

// ---- CSR aggregation: out[d,:] = dinv[d] * sum_{c in N(d)} T16[c,:] + b ---
// one wave per node; lane = (row-group g = lane>>3, dim-slice s = lane&7).
// Wave-cooperative col preload, shfl index distribution, 8-deep masked
// row gathers (all rounds of a 64-batch issued before accumulation).
__device__ __forceinline__ void acc8(float* acc, uint4 u) {
  __half2 h0 = *reinterpret_cast<__half2*>(&u.x);
  __half2 h1 = *reinterpret_cast<__half2*>(&u.y);
  __half2 h2 = *reinterpret_cast<__half2*>(&u.z);
  __half2 h3 = *reinterpret_cast<__half2*>(&u.w);
  float2 f0 = __half22float2(h0);
  float2 f1 = __half22float2(h1);
  float2 f2 = __half22float2(h2);
  float2 f3 = __half22float2(h3);
  acc[0] += f0.x; acc[1] += f0.y;
  acc[2] += f1.x; acc[3] += f1.y;
  acc[4] += f2.x; acc[5] += f2.y;
  acc[6] += f3.x; acc[7] += f3.y;
}

__global__ __launch_bounds__(256) void aggregate_kernel(
    const __half* __restrict__ T, const int* __restrict__ offs,
    const int* __restrict__ col, const float* __restrict__ dinv,
    const float* __restrict__ bias, float* __restrict__ out,
    int n, int relu) {
  int gid = blockIdx.x * blockDim.x + threadIdx.x;
  int wid = gid >> 6;
  if (wid >= n) return;
  int lane = threadIdx.x & 63;
  int g = lane >> 3;          // row group 0..7
  int s = lane & 7;           // dim slice: dims 8s..8s+7
  int j0 = offs[wid], j1 = offs[wid + 1];
  int deg = j1 - j0;
  const __half* Ts = T + s * 8;

  float acc[8];
#pragma unroll
  for (int k = 0; k < 8; ++k) acc[k] = 0.f;

  for (int base = 0; base < deg; base += 64) {
    int idx = base + lane;
    int c_local = (idx < deg) ? col[j0 + idx] : -1;
    int rem = deg - base; if (rem > 64) rem = 64;
    int nr = (rem + 7) >> 3;          // rounds in this batch (wave-uniform)

    int cc[8];
#pragma unroll
    for (int t = 0; t < 8; ++t)
      cc[t] = (t < nr) ? __shfl(c_local, t * 8 + g, 64) : -1;

    uint4 u[8];
#pragma unroll
    for (int t = 0; t < 8; ++t)
      if (cc[t] >= 0)
        u[t] = *reinterpret_cast<const uint4*>(Ts + (size_t)cc[t] * DD);

#pragma unroll
    for (int t = 0; t < 8; ++t)
      if (cc[t] >= 0) acc8(acc, u[t]);
  }

  // reduce over g (lane bits 3,4,5)
#pragma unroll
  for (int m = 8; m <= 32; m <<= 1) {
#pragma unroll
    for (int k = 0; k < 8; ++k)
      acc[k] += __shfl_xor(acc[k], m, 64);
  }

  if (g == 0) {
    float dv = dinv[wid];
    const float4* bp = reinterpret_cast<const float4*>(bias + s * 8);
    float4 b0 = bp[0], b1 = bp[1];
    float4 o0, o1;
    o0.x = fmaf(acc[0], dv, b0.x);
    o0.y = fmaf(acc[1], dv, b0.y);
    o0.z = fmaf(acc[2], dv, b0.z);
    o0.w = fmaf(acc[3], dv, b0.w);
    o1.x = fmaf(acc[4], dv, b1.x);
    o1.y = fmaf(acc[5], dv, b1.y);
    o1.z = fmaf(acc[6], dv, b1.z);
    o1.w = fmaf(acc[7], dv, b1.w);
    if (relu) {
      o0.x = fmaxf(o0.x, 0.f); o0.y = fmaxf(o0.y, 0.f);
      o0.z = fmaxf(o0.z, 0.f); o0.w = fmaxf(o0.w, 0.f);
      o1.x = fmaxf(o1.x, 0.f); o1.y = fmaxf(o1.y, 0.f);
      o1.z = fmaxf(o1.z, 0.f); o1.w = fmaxf(o1.w, 0.f);
    }
    float4* op = reinterpret_cast<float4*>(out + (size_t)wid * DD + s * 8);
    op[0] = o0;
    op[1] = o1;
  }
}

// ---------------------------------------------------------------------------
extern "C" void kernel_launch(void* const* d_in, const int* in_sizes, int n_in,
                              void* d_out, int out_size, void* d_ws, size_t ws_size,
                              hipStream_t stream) {
  const float* x   = (const float*)d_in[0];
  const void*  eix = d_in[1];
  const float* Win = (const float*)d_in[2];
  const float* bin = (const float*)d_in[3];
  const float* W1  = (const float*)d_in[4];
  const float* b1  = (const float*)d_in[5];
  const float* W2  = (const float*)d_in[6];
  const float* b2  = (const float*)d_in[7];
  const float* W3  = (const float*)d_in[8];
  const float* b3  = (const float*)d_in[9];

  int n = in_sizes[0] / DD;
  int E = in_sizes[1] / 2;
  int M = E + n;
  int chunk = (n + NB - 1) / NB;    // local-dst fits 16 bits for n <= 65536

  char* w = (char*)d_ws;
  auto carve = [&](size_t bytes) {
    char* p = w;
    w += (bytes + 255) & ~(size_t)255;
    return p;
  };
  int*          histPB = (int*)carve((size_t)GB * NB * 4);
  int*          offs   = (int*)carve((size_t)(n + 1) * 4);
  float*        dinv   = (float*)carve((size_t)n * 4);
  unsigned int* rec    = (unsigned int*)carve((size_t)E * 4);
  int*          col    = (int*)carve((size_t)M * 4);
  float*        hbuf   = (float*)carve((size_t)n * DD * 4);
  __half*       t16    = (__half*)carve((size_t)n * DD * 2);

  int tile_grid = (n + 63) / 64;
  int agg_grid  = (n * 64 + 255) / 256;

  histA_kernel<<<GB, 256, 0, stream>>>(eix, E, chunk, histPB);
  passB2_kernel<<<GB, 256, 0, stream>>>(eix, E, chunk, histPB, rec);
  // fused: CSR finalize (blocks 0..255) + layer-0 GEMM (blocks 256..)
  passC2_gemm0_kernel<<<NB + tile_grid, 256, 0, stream>>>(
      rec, histPB, offs, dinv, col, n, E, chunk, x, Win, bin, hbuf);

  // conv1 transform: t16 = dinv * (hbuf @ W1)    (fp16)
  gemm_kernel<<<tile_grid, 256, 0, stream>>>(hbuf, W1, nullptr, dinv, nullptr, t16, n);
  aggregate_kernel<<<agg_grid, 256, 0, stream>>>(t16, offs, col, dinv, b1, hbuf, n, 1);
  // conv2
  gemm_kernel<<<tile_grid, 256, 0, stream>>>(hbuf, W2, nullptr, dinv, nullptr, t16, n);
  aggregate_kernel<<<agg_grid, 256, 0, stream>>>(t16, offs, col, dinv, b2, hbuf, n, 1);
  // conv3 (no relu, fp32 out)
  gemm_kernel<<<tile_grid, 256, 0, stream>>>(hbuf, W3, nullptr, dinv, nullptr, t16, n);
  aggregate_kernel<<<agg_grid, 256, 0, stream>>>(t16, offs, col, dinv, b3, (float*)d_out, n, 0);
}

// Round 17
// 215.772 us; speedup vs baseline: 1.1873x; 1.0251x over previous
//
#include <hip/hip_runtime.h>
#include <hip/hip_fp16.h>

#define DD 64
#define NB 256          // buckets (one per passC2 block); requires n <= 65536
#define GB 128          // blocks for histA/passB2

// ---------------------------------------------------------------------------
// Inline int64-vs-int32 detection: first 128 odd u32 words all zero <=> int64.
__device__ __forceinline__ int detect_is64(const unsigned int* p, int E,
                                           int tid, int* sflag) {
  if (tid == 0) *sflag = 1;
  __syncthreads();
  int lim = E < 128 ? E : 128;
  if (tid < lim && p[2 * tid + 1] != 0u) *sflag = 0;
  __syncthreads();
  return *sflag;
}

// ---- histA: per-(block,bucket) histogram of dst ---------------------------
__global__ __launch_bounds__(256) void histA_kernel(
    const void* __restrict__ eidx, int E, int chunk,
    int* __restrict__ histPB) {
  __shared__ int h[NB];
  __shared__ int sflag;
  int tid = threadIdx.x;
  int is64 = detect_is64((const unsigned int*)eidx, E, tid, &sflag);
  h[tid] = 0;
  __syncthreads();
  int seg = (E + GB - 1) / GB;
  int e0 = blockIdx.x * seg;
  int e1 = min(e0 + seg, E);
  for (int e = e0 + tid; e < e1; e += 256) {
    int d;
    if (is64) d = (int)((const long long*)eidx)[e + E];
    else      d = ((const int*)eidx)[e + E];
    atomicAdd(&h[d / chunk], 1);
  }
  __syncthreads();
  histPB[blockIdx.x * NB + tid] = h[tid];
}

// ---- passB2: recompute bases from histPB, then bucketed scatter -----------
__global__ __launch_bounds__(256) void passB2_kernel(
    const void* __restrict__ eidx, int E, int chunk,
    const int* __restrict__ histPB, unsigned int* __restrict__ rec) {
  __shared__ int cur[NB];
  __shared__ int sc[NB];
  __shared__ int sflag;
  int tid = threadIdx.x;
  int blk = blockIdx.x;
  int is64 = detect_is64((const unsigned int*)eidx, E, tid, &sflag);

  // bucket tid: total over all source blocks + prefix over blocks < blk
  int tot = 0, pre = 0;
  for (int t = 0; t < GB; ++t) {
    int v = histPB[t * NB + tid];
    tot += v;
    if (t < blk) pre += v;
  }
  sc[tid] = tot;
  __syncthreads();
  for (int off = 1; off < NB; off <<= 1) {
    int t = (tid >= off) ? sc[tid - off] : 0;
    __syncthreads();
    sc[tid] += t;
    __syncthreads();
  }
  cur[tid] = (sc[tid] - tot) + pre;   // bucketBase + local prefix
  __syncthreads();

  int seg = (E + GB - 1) / GB;
  int e0 = blk * seg;
  int e1 = min(e0 + seg, E);
  for (int e = e0 + tid; e < e1; e += 256) {
    int s, d;
    if (is64) {
      const long long* p = (const long long*)eidx;
      s = (int)p[e];
      d = (int)p[e + E];
    } else {
      const int* p = (const int*)eidx;
      s = p[e];
      d = p[e + E];
    }
    int b = d / chunk;
    int ld = d - b * chunk;
    int pos = atomicAdd(&cur[b], 1);
    rec[pos] = ((unsigned int)s << 16) | (unsigned int)ld;
  }
}

// ---- passC2: recompute bases, then per-bucket CSR finalize ----------------
__global__ __launch_bounds__(256) void passC2_kernel(
    const unsigned int* __restrict__ rec, const int* __restrict__ histPB,
    int* __restrict__ offs, float* __restrict__ dinv, int* __restrict__ col,
    int n, int E, int chunk) {
  int b = blockIdx.x;
  int tid = threadIdx.x;
  __shared__ int sc[NB];
  __shared__ int hist[NB];
  __shared__ int cursor[NB];
  __shared__ int jb0s, jb1s;

  // recompute bucket totals + scan -> this bucket's record range
  int tot = 0;
  for (int t = 0; t < GB; ++t) tot += histPB[t * NB + tid];
  sc[tid] = tot;
  __syncthreads();
  for (int off = 1; off < NB; off <<= 1) {
    int t = (tid >= off) ? sc[tid - off] : 0;
    __syncthreads();
    sc[tid] += t;
    __syncthreads();
  }
  if (tid == b) { jb0s = sc[tid] - tot; jb1s = sc[tid]; }
  __syncthreads();
  int jb0 = jb0s, jb1 = jb1s;

  if (b == 0 && tid == 0) offs[n] = E + n;
  int d0 = b * chunk;
  if (d0 >= n) return;
  int nd = min(chunk, n - d0);
  int cb = jb0 + d0;                 // csrBase (d0 < n here)

  hist[tid] = (tid < nd) ? 1 : 0;    // self-loop seed
  __syncthreads();
  for (int j = jb0 + tid; j < jb1; j += 256)
    atomicAdd(&hist[rec[j] & 0xFFFFu], 1);
  __syncthreads();
  int deg = hist[tid];
  sc[tid] = deg;
  __syncthreads();
  for (int off = 1; off < NB; off <<= 1) {
    int t = (tid >= off) ? sc[tid - off] : 0;
    __syncthreads();
    sc[tid] += t;
    __syncthreads();
  }
  int loc = sc[tid] - deg;           // exclusive prefix
  if (tid < nd) {
    offs[d0 + tid] = cb + loc;
    dinv[d0 + tid] = rsqrtf((float)deg);
    col[cb + loc] = d0 + tid;        // self-loop first
  }
  cursor[tid] = loc + 1;
  __syncthreads();
  for (int j = jb0 + tid; j < jb1; j += 256) {
    unsigned int r = rec[j];
    int p = atomicAdd(&cursor[(int)(r & 0xFFFFu)], 1);
    col[cb + p] = (int)(r >> 16);
  }
}

// ---- dense GEMM: acc = H @ W; epilogue: bias+relu -> fp32, or dinv -> fp16 -
__global__ __launch_bounds__(256) void gemm_kernel(
    const float* __restrict__ H, const float* __restrict__ W,
    const float* __restrict__ bias, const float* __restrict__ dinv,
    float* __restrict__ T32, __half* __restrict__ T16, int n) {
  __shared__ float Ws[64][68];
  __shared__ float Hs[64][68];
  int tid = threadIdx.x;
  int row0 = blockIdx.x * 64;

  for (int i = tid; i < 1024; i += 256) {
    int r = i >> 4, c = (i & 15) << 2;
    *reinterpret_cast<float4*>(&Ws[r][c]) = ((const float4*)W)[i];
    float4 hv = make_float4(0.f, 0.f, 0.f, 0.f);
    if (row0 + r < n)
      hv = *reinterpret_cast<const float4*>(H + (size_t)(row0 + r) * DD + c);
    *reinterpret_cast<float4*>(&Hs[r][c]) = hv;
  }
  __syncthreads();

  int tr = tid >> 4, tc = tid & 15;
  int r0 = tr << 2, c0 = tc << 2;

  float acc[4][4];
#pragma unroll
  for (int i = 0; i < 4; ++i)
#pragma unroll
    for (int j = 0; j < 4; ++j) acc[i][j] = 0.f;

#pragma unroll
  for (int k = 0; k < 64; ++k) {
    float h0 = Hs[r0 + 0][k], h1 = Hs[r0 + 1][k];
    float h2 = Hs[r0 + 2][k], h3 = Hs[r0 + 3][k];
    float4 wv = *reinterpret_cast<const float4*>(&Ws[k][c0]);
    acc[0][0] = fmaf(h0, wv.x, acc[0][0]); acc[0][1] = fmaf(h0, wv.y, acc[0][1]);
    acc[0][2] = fmaf(h0, wv.z, acc[0][2]); acc[0][3] = fmaf(h0, wv.w, acc[0][3]);
    acc[1][0] = fmaf(h1, wv.x, acc[1][0]); acc[1][1] = fmaf(h1, wv.y, acc[1][1]);
    acc[1][2] = fmaf(h1, wv.z, acc[1][2]); acc[1][3] = fmaf(h1, wv.w, acc[1][3]);
    acc[2][0] = fmaf(h2, wv.x, acc[2][0]); acc[2][1] = fmaf(h2, wv.y, acc[2][1]);
    acc[2][2] = fmaf(h2, wv.z, acc[2][2]); acc[2][3] = fmaf(h2, wv.w, acc[2][3]);
    acc[3][0] = fmaf(h3, wv.x, acc[3][0]); acc[3][1] = fmaf(h3, wv.y, acc[3][1]);
    acc[3][2] = fmaf(h3, wv.z, acc[3][2]); acc[3][3] = fmaf(h3, wv.w, acc[3][3]);
  }

  if (T16) {
    // fp16 path: o = dinv[row] * acc
#pragma unroll
    for (int i = 0; i < 4; ++i) {
      long long row = (long long)row0 + r0 + i;
      if (row >= n) break;
      float dv = dinv[row];
      __half2 p01 = __floats2half2_rn(acc[i][0] * dv, acc[i][1] * dv);
      __half2 p23 = __floats2half2_rn(acc[i][2] * dv, acc[i][3] * dv);
      uint2 u;
      u.x = *reinterpret_cast<unsigned int*>(&p01);
      u.y = *reinterpret_cast<unsigned int*>(&p23);
      *reinterpret_cast<uint2*>(T16 + (size_t)row * DD + c0) = u;
    }
  } else {
    // fp32 path: o = relu(acc + bias)
    float4 bv = *reinterpret_cast<const float4*>(bias + c0);
#pragma unroll
    for (int i = 0; i < 4; ++i) {
      long long row = (long long)row0 + r0 + i;
      if (row >= n) break;
      float4 o;
      o.x = fmaxf(acc[i][0] + bv.x, 0.f);
      o.y = fmaxf(acc[i][1] + bv.y, 0.f);
      o.z = fmaxf(acc[i][2] + bv.z, 0.f);
      o.w = fmaxf(acc[i][3] + bv.w, 0.f);
      *reinterpret_cast<float4*>(T32 + (size_t)row * DD + c0) = o;
    }
  }
}

// ---- shared gather core ---------------------------------------------------
__device__ __forceinline__ void acc8(float* acc, uint4 u) {
  __half2 h0 = *reinterpret_cast<__half2*>(&u.x);
  __half2 h1 = *reinterpret_cast<__half2*>(&u.y);
  __half2 h2 = *reinterpret_cast<__half2*>(&u.z);
  __half2 h3 = *reinterpret_cast<__half2*>(&u.w);
  float2 f0 = __half22float2(h0);
  float2 f1 = __half22float2(h1);
  float2 f2 = __half22float2(h2);
  float2 f3 = __half22float2(h3);
  acc[0] += f0.x; acc[1] += f0.y;
  acc[2] += f1.x; acc[3] += f1.y;
  acc[4] += f2.x; acc[5] += f2.y;
  acc[6] += f3.x; acc[7] += f3.y;
}

// gather neighbor-sum for one node into acc[8] (slice s, group g);
// 8-deep masked gathers; after the butterfly ALL lanes hold the full sum
// of dims 8s..8s+7.
__device__ __forceinline__ void gather_node(
    const __half* __restrict__ Ts, const int* __restrict__ col,
    int j0, int deg, int lane, int g, float* acc) {
#pragma unroll
  for (int k = 0; k < 8; ++k) acc[k] = 0.f;
  for (int base = 0; base < deg; base += 64) {
    int idx = base + lane;
    int c_local = (idx < deg) ? col[j0 + idx] : -1;
    int rem = deg - base; if (rem > 64) rem = 64;
    int nr = (rem + 7) >> 3;

    int cc[8];
#pragma unroll
    for (int t = 0; t < 8; ++t)
      cc[t] = (t < nr) ? __shfl(c_local, t * 8 + g, 64) : -1;

    uint4 u[8];
#pragma unroll
    for (int t = 0; t < 8; ++t)
      if (cc[t] >= 0)
        u[t] = *reinterpret_cast<const uint4*>(Ts + (size_t)cc[t] * DD);

#pragma unroll
    for (int t = 0; t < 8; ++t)
      if (cc[t] >= 0) acc8(acc, u[t]);
  }
#pragma unroll
  for (int m = 8; m <= 32; m <<= 1) {
#pragma unroll
    for (int k = 0; k < 8; ++k)
      acc[k] += __shfl_xor(acc[k], m, 64);
  }
}

// ---- fused aggregate + next transform, wave:node = 1:1 --------------------
// Tout[node,:] = (dinv (*) relu(dinv*agg(Tin)+b)) @ Wn   (fp16 out)
// block = 4 waves = 4 nodes; q handoff via 1 KB LDS; W read coalesced (L1).
__global__ __launch_bounds__(256) void aggG_kernel(
    const __half* __restrict__ Tin, const int* __restrict__ offs,
    const int* __restrict__ col, const float* __restrict__ dinv,
    const float* __restrict__ bias, const float* __restrict__ Wn,
    __half* __restrict__ Tout, int n) {
  __shared__ float qs[4][64];
  int tid = threadIdx.x;
  int wv = tid >> 6;
  int lane = tid & 63;
  int g = lane >> 3, s = lane & 7;
  int wid = blockIdx.x * 4 + wv;
  bool active = (wid < n);

  if (active) {
    int j0 = offs[wid], j1 = offs[wid + 1];
    float acc[8];
    gather_node(Tin + s * 8, col, j0, j1 - j0, lane, g, acc);
    if (g == 0) {
      float dv = dinv[wid];
      const float4* bp = reinterpret_cast<const float4*>(bias + s * 8);
      float4 b0 = bp[0], b1v = bp[1];
      float4 q0, q1;
      q0.x = fmaxf(fmaf(acc[0], dv, b0.x), 0.f) * dv;
      q0.y = fmaxf(fmaf(acc[1], dv, b0.y), 0.f) * dv;
      q0.z = fmaxf(fmaf(acc[2], dv, b0.z), 0.f) * dv;
      q0.w = fmaxf(fmaf(acc[3], dv, b0.w), 0.f) * dv;
      q1.x = fmaxf(fmaf(acc[4], dv, b1v.x), 0.f) * dv;
      q1.y = fmaxf(fmaf(acc[5], dv, b1v.y), 0.f) * dv;
      q1.z = fmaxf(fmaf(acc[6], dv, b1v.z), 0.f) * dv;
      q1.w = fmaxf(fmaf(acc[7], dv, b1v.w), 0.f) * dv;
      *reinterpret_cast<float4*>(&qs[wv][s * 8])     = q0;
      *reinterpret_cast<float4*>(&qs[wv][s * 8 + 4]) = q1;
    }
  }
  __syncthreads();

  if (active) {
    // lane computes output column `lane`: o = sum_k q[k] * W[k][lane]
    float o0 = 0.f, o1 = 0.f, o2 = 0.f, o3 = 0.f;
#pragma unroll
    for (int k = 0; k < 64; k += 4) {
      o0 = fmaf(qs[wv][k + 0], Wn[(k + 0) * DD + lane], o0);
      o1 = fmaf(qs[wv][k + 1], Wn[(k + 1) * DD + lane], o1);
      o2 = fmaf(qs[wv][k + 2], Wn[(k + 2) * DD + lane], o2);
      o3 = fmaf(qs[wv][k + 3], Wn[(k + 3) * DD + lane], o3);
    }
    float o = (o0 + o1) + (o2 + o3);
    Tout[(size_t)wid * DD + lane] = __float2half_rn(o);
  }
}

// ---- final CSR aggregation: out = dinv*agg(T) + b (fp32, no relu) ---------
__global__ __launch_bounds__(256) void aggregate_kernel(
    const __half* __restrict__ T, const int* __restrict__ offs,
    const int* __restrict__ col, const float* __restrict__ dinv,
    const float* __restrict__ bias, float* __restrict__ out, int n) {
  int gid = blockIdx.x * blockDim.x + threadIdx.x;
  int wid = gid >> 6;
  if (wid >= n) return;
  int lane = threadIdx.x & 63;
  int g = lane >> 3, s = lane & 7;
  int j0 = offs[wid], j1 = offs[wid + 1];
  float acc[8];
  gather_node(T + s * 8, col, j0, j1 - j0, lane, g, acc);

  if (g == 0) {
    float dv = dinv[wid];
    const float4* bp = reinterpret_cast<const float4*>(bias + s * 8);
    float4 b0 = bp[0], b1 = bp[1];
    float4 o0, o1;
    o0.x = fmaf(acc[0], dv, b0.x);
    o0.y = fmaf(acc[1], dv, b0.y);
    o0.z = fmaf(acc[2], dv, b0.z);
    o0.w = fmaf(acc[3], dv, b0.w);
    o1.x = fmaf(acc[4], dv, b1.x);
    o1.y = fmaf(acc[5], dv, b1.y);
    o1.z = fmaf(acc[6], dv, b1.z);
    o1.w = fmaf(acc[7], dv, b1.w);
    float4* op = reinterpret_cast<float4*>(out + (size_t)wid * DD + s * 8);
    op[0] = o0;
    op[1] = o1;
  }
}

// ---------------------------------------------------------------------------
extern "C" void kernel_launch(void* const* d_in, const int* in_sizes, int n_in,
                              void* d_out, int out_size, void* d_ws, size_t ws_size,
                              hipStream_t stream) {
  const float* x   = (const float*)d_in[0];
  const void*  eix = d_in[1];
  const float* Win = (const float*)d_in[2];
  const float* bin = (const float*)d_in[3];
  const float* W1  = (const float*)d_in[4];
  const float* b1  = (const float*)d_in[5];
  const float* W2  = (const float*)d_in[6];
  const float* b2  = (const float*)d_in[7];
  const float* W3  = (const float*)d_in[8];
  const float* b3  = (const float*)d_in[9];

  int n = in_sizes[0] / DD;
  int E = in_sizes[1] / 2;
  int M = E + n;
  int chunk = (n + NB - 1) / NB;    // local-dst fits 16 bits for n <= 65536

  char* w = (char*)d_ws;
  auto carve = [&](size_t bytes) {
    char* p = w;
    w += (bytes + 255) & ~(size_t)255;
    return p;
  };
  int*          histPB = (int*)carve((size_t)GB * NB * 4);
  int*          offs   = (int*)carve((size_t)(n + 1) * 4);
  float*        dinv   = (float*)carve((size_t)n * 4);
  unsigned int* rec    = (unsigned int*)carve((size_t)E * 4);
  int*          col    = (int*)carve((size_t)M * 4);
  float*        hbuf   = (float*)carve((size_t)n * DD * 4);
  __half*       t16a   = (__half*)carve((size_t)n * DD * 2);
  __half*       t16b   = (__half*)carve((size_t)n * DD * 2);

  int tile_grid = (n + 63) / 64;
  int node_grid = (n + 3) / 4;
  int agg_grid  = (n * 64 + 255) / 256;

  histA_kernel<<<GB, 256, 0, stream>>>(eix, E, chunk, histPB);
  passB2_kernel<<<GB, 256, 0, stream>>>(eix, E, chunk, histPB, rec);
  passC2_kernel<<<NB, 256, 0, stream>>>(rec, histPB, offs, dinv, col, n, E, chunk);

  // layer 0: hbuf = relu(x @ Win + bin)          (fp32)
  gemm_kernel<<<tile_grid, 256, 0, stream>>>(x, Win, bin, nullptr, hbuf, nullptr, n);
  // conv1 transform: t16a = dinv * (hbuf @ W1)   (fp16)
  gemm_kernel<<<tile_grid, 256, 0, stream>>>(hbuf, W1, nullptr, dinv, nullptr, t16a, n);
  // conv1 aggregate + conv2 transform: t16b = (dinv (*) relu(dinv*agg(t16a)+b1)) @ W2
  aggG_kernel<<<node_grid, 256, 0, stream>>>(t16a, offs, col, dinv, b1, W2, t16b, n);
  // conv2 aggregate + conv3 transform: t16a = (dinv (*) relu(dinv*agg(t16b)+b2)) @ W3
  aggG_kernel<<<node_grid, 256, 0, stream>>>(t16b, offs, col, dinv, b2, W3, t16a, n);
  // conv3 aggregate: out = dinv*agg(t16a) + b3   (fp32, no relu)
  aggregate_kernel<<<agg_grid, 256, 0, stream>>>(t16a, offs, col, dinv, b3, (float*)d_out, n);
}

// Round 18
// 212.333 us; speedup vs baseline: 1.2065x; 1.0162x over previous
//
#include <hip/hip_runtime.h>
#include <hip/hip_fp16.h>

#define DD 64
#define NB 256          // buckets (one per passC2 block); requires n <= 65536
#define GB 128          // blocks for histA/passB2

// ---------------------------------------------------------------------------
// Inline int64-vs-int32 detection: first 128 odd u32 words all zero <=> int64.
__device__ __forceinline__ int detect_is64(const unsigned int* p, int E,
                                           int tid, int* sflag) {
  if (tid == 0) *sflag = 1;
  __syncthreads();
  int lim = E < 128 ? E : 128;
  if (tid < lim && p[2 * tid + 1] != 0u) *sflag = 0;
  __syncthreads();
  return *sflag;
}

// ---- histA: per-(block,bucket) histogram of dst ---------------------------
__global__ __launch_bounds__(256) void histA_kernel(
    const void* __restrict__ eidx, int E, int chunk,
    int* __restrict__ histPB) {
  __shared__ int h[NB];
  __shared__ int sflag;
  int tid = threadIdx.x;
  int is64 = detect_is64((const unsigned int*)eidx, E, tid, &sflag);
  h[tid] = 0;
  __syncthreads();
  int seg = (E + GB - 1) / GB;
  int e0 = blockIdx.x * seg;
  int e1 = min(e0 + seg, E);
  for (int e = e0 + tid; e < e1; e += 256) {
    int d;
    if (is64) d = (int)((const long long*)eidx)[e + E];
    else      d = ((const int*)eidx)[e + E];
    atomicAdd(&h[d / chunk], 1);
  }
  __syncthreads();
  histPB[blockIdx.x * NB + tid] = h[tid];
}

// ---- passB2: recompute bases from histPB, then bucketed scatter -----------
__global__ __launch_bounds__(256) void passB2_kernel(
    const void* __restrict__ eidx, int E, int chunk,
    const int* __restrict__ histPB, unsigned int* __restrict__ rec) {
  __shared__ int cur[NB];
  __shared__ int sc[NB];
  __shared__ int sflag;
  int tid = threadIdx.x;
  int blk = blockIdx.x;
  int is64 = detect_is64((const unsigned int*)eidx, E, tid, &sflag);

  // bucket tid: total over all source blocks + prefix over blocks < blk
  int tot = 0, pre = 0;
  for (int t = 0; t < GB; ++t) {
    int v = histPB[t * NB + tid];
    tot += v;
    if (t < blk) pre += v;
  }
  sc[tid] = tot;
  __syncthreads();
  for (int off = 1; off < NB; off <<= 1) {
    int t = (tid >= off) ? sc[tid - off] : 0;
    __syncthreads();
    sc[tid] += t;
    __syncthreads();
  }
  cur[tid] = (sc[tid] - tot) + pre;   // bucketBase + local prefix
  __syncthreads();

  int seg = (E + GB - 1) / GB;
  int e0 = blk * seg;
  int e1 = min(e0 + seg, E);
  for (int e = e0 + tid; e < e1; e += 256) {
    int s, d;
    if (is64) {
      const long long* p = (const long long*)eidx;
      s = (int)p[e];
      d = (int)p[e + E];
    } else {
      const int* p = (const int*)eidx;
      s = p[e];
      d = p[e + E];
    }
    int b = d / chunk;
    int ld = d - b * chunk;
    int pos = atomicAdd(&cur[b], 1);
    rec[pos] = ((unsigned int)s << 16) | (unsigned int)ld;
  }
}

// ---- passC2: recompute bases, then per-bucket CSR finalize ----------------
__global__ __launch_bounds__(256) void passC2_kernel(
    const unsigned int* __restrict__ rec, const int* __restrict__ histPB,
    int* __restrict__ offs, float* __restrict__ dinv, int* __restrict__ col,
    int n, int E, int chunk) {
  int b = blockIdx.x;
  int tid = threadIdx.x;
  __shared__ int sc[NB];
  __shared__ int hist[NB];
  __shared__ int cursor[NB];
  __shared__ int jb0s, jb1s;

  // recompute bucket totals + scan -> this bucket's record range
  int tot = 0;
  for (int t = 0; t < GB; ++t) tot += histPB[t * NB + tid];
  sc[tid] = tot;
  __syncthreads();
  for (int off = 1; off < NB; off <<= 1) {
    int t = (tid >= off) ? sc[tid - off] : 0;
    __syncthreads();
    sc[tid] += t;
    __syncthreads();
  }
  if (tid == b) { jb0s = sc[tid] - tot; jb1s = sc[tid]; }
  __syncthreads();
  int jb0 = jb0s, jb1 = jb1s;

  if (b == 0 && tid == 0) offs[n] = E + n;
  int d0 = b * chunk;
  if (d0 >= n) return;
  int nd = min(chunk, n - d0);
  int cb = jb0 + d0;                 // csrBase (d0 < n here)

  hist[tid] = (tid < nd) ? 1 : 0;    // self-loop seed
  __syncthreads();
  for (int j = jb0 + tid; j < jb1; j += 256)
    atomicAdd(&hist[rec[j] & 0xFFFFu], 1);
  __syncthreads();
  int deg = hist[tid];
  sc[tid] = deg;
  __syncthreads();
  for (int off = 1; off < NB; off <<= 1) {
    int t = (tid >= off) ? sc[tid - off] : 0;
    __syncthreads();
    sc[tid] += t;
    __syncthreads();
  }
  int loc = sc[tid] - deg;           // exclusive prefix
  if (tid < nd) {
    offs[d0 + tid] = cb + loc;
    dinv[d0 + tid] = rsqrtf((float)deg);
    col[cb + loc] = d0 + tid;        // self-loop first
  }
  cursor[tid] = loc + 1;
  __syncthreads();
  for (int j = jb0 + tid; j < jb1; j += 256) {
    unsigned int r = rec[j];
    int p = atomicAdd(&cursor[(int)(r & 0xFFFFu)], 1);
    col[cb + p] = (int)(r >> 16);
  }
}

// ---- dense GEMM: acc = H @ W; epilogue: bias+relu -> fp32, or dinv -> fp16 -
// H tile staged TRANSPOSED (HsT[k][r]) so the inner loop is 2x ds_read_b128
// per k-step (was 4x b32 + 1x b128) -- LDS-read-bound fix.
__global__ __launch_bounds__(256) void gemm_kernel(
    const float* __restrict__ H, const float* __restrict__ W,
    const float* __restrict__ bias, const float* __restrict__ dinv,
    float* __restrict__ T32, __half* __restrict__ T16, int n) {
  __shared__ float Ws[64][68];
  __shared__ float HsT[64][68];     // HsT[k][r] = H[row0+r][k]
  int tid = threadIdx.x;
  int row0 = blockIdx.x * 64;

  for (int i = tid; i < 1024; i += 256) {
    int r = i >> 4, c = (i & 15) << 2;
    *reinterpret_cast<float4*>(&Ws[r][c]) = ((const float4*)W)[i];
    float4 hv = make_float4(0.f, 0.f, 0.f, 0.f);
    if (row0 + r < n)
      hv = *reinterpret_cast<const float4*>(H + (size_t)(row0 + r) * DD + c);
    HsT[c + 0][r] = hv.x;
    HsT[c + 1][r] = hv.y;
    HsT[c + 2][r] = hv.z;
    HsT[c + 3][r] = hv.w;
  }
  __syncthreads();

  int tr = tid >> 4, tc = tid & 15;
  int r0 = tr << 2, c0 = tc << 2;

  float acc[4][4];
#pragma unroll
  for (int i = 0; i < 4; ++i)
#pragma unroll
    for (int j = 0; j < 4; ++j) acc[i][j] = 0.f;

#pragma unroll
  for (int k = 0; k < 64; ++k) {
    float4 h = *reinterpret_cast<const float4*>(&HsT[k][r0]);
    float4 wv = *reinterpret_cast<const float4*>(&Ws[k][c0]);
    acc[0][0] = fmaf(h.x, wv.x, acc[0][0]); acc[0][1] = fmaf(h.x, wv.y, acc[0][1]);
    acc[0][2] = fmaf(h.x, wv.z, acc[0][2]); acc[0][3] = fmaf(h.x, wv.w, acc[0][3]);
    acc[1][0] = fmaf(h.y, wv.x, acc[1][0]); acc[1][1] = fmaf(h.y, wv.y, acc[1][1]);
    acc[1][2] = fmaf(h.y, wv.z, acc[1][2]); acc[1][3] = fmaf(h.y, wv.w, acc[1][3]);
    acc[2][0] = fmaf(h.z, wv.x, acc[2][0]); acc[2][1] = fmaf(h.z, wv.y, acc[2][1]);
    acc[2][2] = fmaf(h.z, wv.z, acc[2][2]); acc[2][3] = fmaf(h.z, wv.w, acc[2][3]);
    acc[3][0] = fmaf(h.w, wv.x, acc[3][0]); acc[3][1] = fmaf(h.w, wv.y, acc[3][1]);
    acc[3][2] = fmaf(h.w, wv.z, acc[3][2]); acc[3][3] = fmaf(h.w, wv.w, acc[3][3]);
  }

  if (T16) {
    // fp16 path: o = dinv[row] * acc
#pragma unroll
    for (int i = 0; i < 4; ++i) {
      long long row = (long long)row0 + r0 + i;
      if (row >= n) break;
      float dv = dinv[row];
      __half2 p01 = __floats2half2_rn(acc[i][0] * dv, acc[i][1] * dv);
      __half2 p23 = __floats2half2_rn(acc[i][2] * dv, acc[i][3] * dv);
      uint2 u;
      u.x = *reinterpret_cast<unsigned int*>(&p01);
      u.y = *reinterpret_cast<unsigned int*>(&p23);
      *reinterpret_cast<uint2*>(T16 + (size_t)row * DD + c0) = u;
    }
  } else {
    // fp32 path: o = relu(acc + bias)
    float4 bv = *reinterpret_cast<const float4*>(bias + c0);
#pragma unroll
    for (int i = 0; i < 4; ++i) {
      long long row = (long long)row0 + r0 + i;
      if (row >= n) break;
      float4 o;
      o.x = fmaxf(acc[i][0] + bv.x, 0.f);
      o.y = fmaxf(acc[i][1] + bv.y, 0.f);
      o.z = fmaxf(acc[i][2] + bv.z, 0.f);
      o.w = fmaxf(acc[i][3] + bv.w, 0.f);
      *reinterpret_cast<float4*>(T32 + (size_t)row * DD + c0) = o;
    }
  }
}

// ---- CSR aggregation: out[d,:] = dinv[d] * sum_{c in N(d)} T16[c,:] + b ---
// one wave per node; lane = (row-group g = lane>>3, dim-slice s = lane&7).
// Wave-cooperative col preload, shfl index distribution, 8-deep masked
// row gathers (all rounds of a 64-batch issued before accumulation).
__device__ __forceinline__ void acc8(float* acc, uint4 u) {
  __half2 h0 = *reinterpret_cast<__half2*>(&u.x);
  __half2 h1 = *reinterpret_cast<__half2*>(&u.y);
  __half2 h2 = *reinterpret_cast<__half2*>(&u.z);
  __half2 h3 = *reinterpret_cast<__half2*>(&u.w);
  float2 f0 = __half22float2(h0);
  float2 f1 = __half22float2(h1);
  float2 f2 = __half22float2(h2);
  float2 f3 = __half22float2(h3);
  acc[0] += f0.x; acc[1] += f0.y;
  acc[2] += f1.x; acc[3] += f1.y;
  acc[4] += f2.x; acc[5] += f2.y;
  acc[6] += f3.x; acc[7] += f3.y;
}

__global__ __launch_bounds__(256) void aggregate_kernel(
    const __half* __restrict__ T, const int* __restrict__ offs,
    const int* __restrict__ col, const float* __restrict__ dinv,
    const float* __restrict__ bias, float* __restrict__ out,
    int n, int relu) {
  int gid = blockIdx.x * blockDim.x + threadIdx.x;
  int wid = gid >> 6;
  if (wid >= n) return;
  int lane = threadIdx.x & 63;
  int g = lane >> 3;          // row group 0..7
  int s = lane & 7;           // dim slice: dims 8s..8s+7
  int j0 = offs[wid], j1 = offs[wid + 1];
  int deg = j1 - j0;
  const __half* Ts = T + s * 8;

  float acc[8];
#pragma unroll
  for (int k = 0; k < 8; ++k) acc[k] = 0.f;

  for (int base = 0; base < deg; base += 64) {
    int idx = base + lane;
    int c_local = (idx < deg) ? col[j0 + idx] : -1;
    int rem = deg - base; if (rem > 64) rem = 64;
    int nr = (rem + 7) >> 3;          // rounds in this batch (wave-uniform)

    int cc[8];
#pragma unroll
    for (int t = 0; t < 8; ++t)
      cc[t] = (t < nr) ? __shfl(c_local, t * 8 + g, 64) : -1;

    uint4 u[8];
#pragma unroll
    for (int t = 0; t < 8; ++t)
      if (cc[t] >= 0)
        u[t] = *reinterpret_cast<const uint4*>(Ts + (size_t)cc[t] * DD);

#pragma unroll
    for (int t = 0; t < 8; ++t)
      if (cc[t] >= 0) acc8(acc, u[t]);
  }

  // reduce over g (lane bits 3,4,5)
#pragma unroll
  for (int m = 8; m <= 32; m <<= 1) {
#pragma unroll
    for (int k = 0; k < 8; ++k)
      acc[k] += __shfl_xor(acc[k], m, 64);
  }

  if (g == 0) {
    float dv = dinv[wid];
    const float4* bp = reinterpret_cast<const float4*>(bias + s * 8);
    float4 b0 = bp[0], b1 = bp[1];
    float4 o0, o1;
    o0.x = fmaf(acc[0], dv, b0.x);
    o0.y = fmaf(acc[1], dv, b0.y);
    o0.z = fmaf(acc[2], dv, b0.z);
    o0.w = fmaf(acc[3], dv, b0.w);
    o1.x = fmaf(acc[4], dv, b1.x);
    o1.y = fmaf(acc[5], dv, b1.y);
    o1.z = fmaf(acc[6], dv, b1.z);
    o1.w = fmaf(acc[7], dv, b1.w);
    if (relu) {
      o0.x = fmaxf(o0.x, 0.f); o0.y = fmaxf(o0.y, 0.f);
      o0.z = fmaxf(o0.z, 0.f); o0.w = fmaxf(o0.w, 0.f);
      o1.x = fmaxf(o1.x, 0.f); o1.y = fmaxf(o1.y, 0.f);
      o1.z = fmaxf(o1.z, 0.f); o1.w = fmaxf(o1.w, 0.f);
    }
    float4* op = reinterpret_cast<float4*>(out + (size_t)wid * DD + s * 8);
    op[0] = o0;
    op[1] = o1;
  }
}

// ---------------------------------------------------------------------------
extern "C" void kernel_launch(void* const* d_in, const int* in_sizes, int n_in,
                              void* d_out, int out_size, void* d_ws, size_t ws_size,
                              hipStream_t stream) {
  const float* x   = (const float*)d_in[0];
  const void*  eix = d_in[1];
  const float* Win = (const float*)d_in[2];
  const float* bin = (const float*)d_in[3];
  const float* W1  = (const float*)d_in[4];
  const float* b1  = (const float*)d_in[5];
  const float* W2  = (const float*)d_in[6];
  const float* b2  = (const float*)d_in[7];
  const float* W3  = (const float*)d_in[8];
  const float* b3  = (const float*)d_in[9];

  int n = in_sizes[0] / DD;
  int E = in_sizes[1] / 2;
  int M = E + n;
  int chunk = (n + NB - 1) / NB;    // local-dst fits 16 bits for n <= 65536

  char* w = (char*)d_ws;
  auto carve = [&](size_t bytes) {
    char* p = w;
    w += (bytes + 255) & ~(size_t)255;
    return p;
  };
  int*          histPB = (int*)carve((size_t)GB * NB * 4);
  int*          offs   = (int*)carve((size_t)(n + 1) * 4);
  float*        dinv   = (float*)carve((size_t)n * 4);
  unsigned int* rec    = (unsigned int*)carve((size_t)E * 4);
  int*          col    = (int*)carve((size_t)M * 4);
  float*        hbuf   = (float*)carve((size_t)n * DD * 4);
  __half*       t16    = (__half*)carve((size_t)n * DD * 2);

  histA_kernel<<<GB, 256, 0, stream>>>(eix, E, chunk, histPB);
  passB2_kernel<<<GB, 256, 0, stream>>>(eix, E, chunk, histPB, rec);
  passC2_kernel<<<NB, 256, 0, stream>>>(rec, histPB, offs, dinv, col, n, E, chunk);

  int tile_grid = (n + 63) / 64;
  int agg_grid  = (n * 64 + 255) / 256;

  // layer 0: hbuf = relu(x @ Win + bin)          (fp32)
  gemm_kernel<<<tile_grid, 256, 0, stream>>>(x, Win, bin, nullptr, hbuf, nullptr, n);
  // conv1 transform: t16 = dinv * (hbuf @ W1)    (fp16)
  gemm_kernel<<<tile_grid, 256, 0, stream>>>(hbuf, W1, nullptr, dinv, nullptr, t16, n);
  aggregate_kernel<<<agg_grid, 256, 0, stream>>>(t16, offs, col, dinv, b1, hbuf, n, 1);
  // conv2
  gemm_kernel<<<tile_grid, 256, 0, stream>>>(hbuf, W2, nullptr, dinv, nullptr, t16, n);
  aggregate_kernel<<<agg_grid, 256, 0, stream>>>(t16, offs, col, dinv, b2, hbuf, n, 1);
  // conv3 (no relu, fp32 out)
  gemm_kernel<<<tile_grid, 256, 0, stream>>>(hbuf, W3, nullptr, dinv, nullptr, t16, n);
  aggregate_kernel<<<agg_grid, 256, 0, stream>>>(t16, offs, col, dinv, b3, (float*)d_out, n, 0);
}

// Round 19
// 209.409 us; speedup vs baseline: 1.2234x; 1.0140x over previous
//
#include <hip/hip_runtime.h>
#include <hip/hip_fp16.h>

#define DD 64
#define NB 256          // buckets (one per passC2 block); requires n <= 65536
#define GB 128          // blocks for histA/passB2

// ---------------------------------------------------------------------------
// Inline int64-vs-int32 detection: first 128 odd u32 words all zero <=> int64.
__device__ __forceinline__ int detect_is64(const unsigned int* p, int E,
                                           int tid, int* sflag) {
  if (tid == 0) *sflag = 1;
  __syncthreads();
  int lim = E < 128 ? E : 128;
  if (tid < lim && p[2 * tid + 1] != 0u) *sflag = 0;
  __syncthreads();
  return *sflag;
}

// ---- histA: per-(block,bucket) histogram of dst ---------------------------
__global__ __launch_bounds__(256) void histA_kernel(
    const void* __restrict__ eidx, int E, int chunk,
    int* __restrict__ histPB) {
  __shared__ int h[NB];
  __shared__ int sflag;
  int tid = threadIdx.x;
  int is64 = detect_is64((const unsigned int*)eidx, E, tid, &sflag);
  h[tid] = 0;
  __syncthreads();
  int seg = (E + GB - 1) / GB;
  int e0 = blockIdx.x * seg;
  int e1 = min(e0 + seg, E);
  for (int e = e0 + tid; e < e1; e += 256) {
    int d;
    if (is64) d = (int)((const long long*)eidx)[e + E];
    else      d = ((const int*)eidx)[e + E];
    atomicAdd(&h[d / chunk], 1);
  }
  __syncthreads();
  histPB[blockIdx.x * NB + tid] = h[tid];
}

// ---- passB2: recompute bases from histPB, then bucketed scatter -----------
__global__ __launch_bounds__(256) void passB2_kernel(
    const void* __restrict__ eidx, int E, int chunk,
    const int* __restrict__ histPB, unsigned int* __restrict__ rec) {
  __shared__ int cur[NB];
  __shared__ int sc[NB];
  __shared__ int sflag;
  int tid = threadIdx.x;
  int blk = blockIdx.x;
  int is64 = detect_is64((const unsigned int*)eidx, E, tid, &sflag);

  // bucket tid: total over all source blocks + prefix over blocks < blk
  int tot = 0, pre = 0;
  for (int t = 0; t < GB; ++t) {
    int v = histPB[t * NB + tid];
    tot += v;
    if (t < blk) pre += v;
  }
  sc[tid] = tot;
  __syncthreads();
  for (int off = 1; off < NB; off <<= 1) {
    int t = (tid >= off) ? sc[tid - off] : 0;
    __syncthreads();
    sc[tid] += t;
    __syncthreads();
  }
  cur[tid] = (sc[tid] - tot) + pre;   // bucketBase + local prefix
  __syncthreads();

  int seg = (E + GB - 1) / GB;
  int e0 = blk * seg;
  int e1 = min(e0 + seg, E);
  for (int e = e0 + tid; e < e1; e += 256) {
    int s, d;
    if (is64) {
      const long long* p = (const long long*)eidx;
      s = (int)p[e];
      d = (int)p[e + E];
    } else {
      const int* p = (const int*)eidx;
      s = p[e];
      d = p[e + E];
    }
    int b = d / chunk;
    int ld = d - b * chunk;
    int pos = atomicAdd(&cur[b], 1);
    rec[pos] = ((unsigned int)s << 16) | (unsigned int)ld;
  }
}

// ---- passC2: recompute bases, then per-bucket CSR finalize ----------------
__global__ __launch_bounds__(256) void passC2_kernel(
    const unsigned int* __restrict__ rec, const int* __restrict__ histPB,
    int* __restrict__ offs, float* __restrict__ dinv, int* __restrict__ col,
    int n, int E, int chunk) {
  int b = blockIdx.x;
  int tid = threadIdx.x;
  __shared__ int sc[NB];
  __shared__ int hist[NB];
  __shared__ int cursor[NB];
  __shared__ int jb0s, jb1s;

  // recompute bucket totals + scan -> this bucket's record range
  int tot = 0;
  for (int t = 0; t < GB; ++t) tot += histPB[t * NB + tid];
  sc[tid] = tot;
  __syncthreads();
  for (int off = 1; off < NB; off <<= 1) {
    int t = (tid >= off) ? sc[tid - off] : 0;
    __syncthreads();
    sc[tid] += t;
    __syncthreads();
  }
  if (tid == b) { jb0s = sc[tid] - tot; jb1s = sc[tid]; }
  __syncthreads();
  int jb0 = jb0s, jb1 = jb1s;

  if (b == 0 && tid == 0) offs[n] = E + n;
  int d0 = b * chunk;
  if (d0 >= n) return;
  int nd = min(chunk, n - d0);
  int cb = jb0 + d0;                 // csrBase (d0 < n here)

  hist[tid] = (tid < nd) ? 1 : 0;    // self-loop seed
  __syncthreads();
  for (int j = jb0 + tid; j < jb1; j += 256)
    atomicAdd(&hist[rec[j] & 0xFFFFu], 1);
  __syncthreads();
  int deg = hist[tid];
  sc[tid] = deg;
  __syncthreads();
  for (int off = 1; off < NB; off <<= 1) {
    int t = (tid >= off) ? sc[tid - off] : 0;
    __syncthreads();
    sc[tid] += t;
    __syncthreads();
  }
  int loc = sc[tid] - deg;           // exclusive prefix
  if (tid < nd) {
    offs[d0 + tid] = cb + loc;
    dinv[d0 + tid] = rsqrtf((float)deg);
    col[cb + loc] = d0 + tid;        // self-loop first
  }
  cursor[tid] = loc + 1;
  __syncthreads();
  for (int j = jb0 + tid; j < jb1; j += 256) {
    unsigned int r = rec[j];
    int p = atomicAdd(&cursor[(int)(r & 0xFFFFu)], 1);
    col[cb + p] = (int)(r >> 16);
  }
}

// ---- fused layer0 + transform1: T16 = dinv * (relu(x@Win + bin) @ W1) -----
// 32-row tile, 256 threads (thread = 1 row x 8 cols), 26 KB LDS, ~40 VGPR.
__global__ __launch_bounds__(256) void gemm01_kernel(
    const float* __restrict__ X, const float* __restrict__ Win,
    const float* __restrict__ bin, const float* __restrict__ W1,
    const float* __restrict__ dinv, __half* __restrict__ T16, int n) {
  __shared__ float Ws[64][68];
  __shared__ float Hs[32][68];
  int tid = threadIdx.x;
  int row0 = blockIdx.x * 32;

  for (int i = tid; i < 1024; i += 256) {
    int r = i >> 4, c = (i & 15) << 2;
    *reinterpret_cast<float4*>(&Ws[r][c]) = ((const float4*)Win)[i];
  }
  for (int i = tid; i < 512; i += 256) {
    int r = i >> 4, c = (i & 15) << 2;
    float4 hv = make_float4(0.f, 0.f, 0.f, 0.f);
    if (row0 + r < n)
      hv = *reinterpret_cast<const float4*>(X + (size_t)(row0 + r) * DD + c);
    *reinterpret_cast<float4*>(&Hs[r][c]) = hv;
  }
  __syncthreads();

  int r = tid >> 3;          // 0..31
  int c0 = (tid & 7) << 3;   // cols c0..c0+7

  float acc[8];
#pragma unroll
  for (int j = 0; j < 8; ++j) acc[j] = 0.f;
#pragma unroll
  for (int k = 0; k < 64; ++k) {
    float hv = Hs[r][k];
    float4 w0 = *reinterpret_cast<const float4*>(&Ws[k][c0]);
    float4 w1 = *reinterpret_cast<const float4*>(&Ws[k][c0 + 4]);
    acc[0] = fmaf(hv, w0.x, acc[0]); acc[1] = fmaf(hv, w0.y, acc[1]);
    acc[2] = fmaf(hv, w0.z, acc[2]); acc[3] = fmaf(hv, w0.w, acc[3]);
    acc[4] = fmaf(hv, w1.x, acc[4]); acc[5] = fmaf(hv, w1.y, acc[5]);
    acc[6] = fmaf(hv, w1.z, acc[6]); acc[7] = fmaf(hv, w1.w, acc[7]);
  }
  // h = relu(acc + bin)
  float4 b0 = *reinterpret_cast<const float4*>(bin + c0);
  float4 b1v = *reinterpret_cast<const float4*>(bin + c0 + 4);
  float h[8];
  h[0] = fmaxf(acc[0] + b0.x, 0.f);  h[1] = fmaxf(acc[1] + b0.y, 0.f);
  h[2] = fmaxf(acc[2] + b0.z, 0.f);  h[3] = fmaxf(acc[3] + b0.w, 0.f);
  h[4] = fmaxf(acc[4] + b1v.x, 0.f); h[5] = fmaxf(acc[5] + b1v.y, 0.f);
  h[6] = fmaxf(acc[6] + b1v.z, 0.f); h[7] = fmaxf(acc[7] + b1v.w, 0.f);
  __syncthreads();           // everyone done reading Hs/Ws

  *reinterpret_cast<float4*>(&Hs[r][c0])     = make_float4(h[0], h[1], h[2], h[3]);
  *reinterpret_cast<float4*>(&Hs[r][c0 + 4]) = make_float4(h[4], h[5], h[6], h[7]);
  for (int i = tid; i < 1024; i += 256) {
    int rr = i >> 4, c = (i & 15) << 2;
    *reinterpret_cast<float4*>(&Ws[rr][c]) = ((const float4*)W1)[i];
  }
  __syncthreads();

#pragma unroll
  for (int j = 0; j < 8; ++j) acc[j] = 0.f;
#pragma unroll
  for (int k = 0; k < 64; ++k) {
    float hv = Hs[r][k];
    float4 w0 = *reinterpret_cast<const float4*>(&Ws[k][c0]);
    float4 w1 = *reinterpret_cast<const float4*>(&Ws[k][c0 + 4]);
    acc[0] = fmaf(hv, w0.x, acc[0]); acc[1] = fmaf(hv, w0.y, acc[1]);
    acc[2] = fmaf(hv, w0.z, acc[2]); acc[3] = fmaf(hv, w0.w, acc[3]);
    acc[4] = fmaf(hv, w1.x, acc[4]); acc[5] = fmaf(hv, w1.y, acc[5]);
    acc[6] = fmaf(hv, w1.z, acc[6]); acc[7] = fmaf(hv, w1.w, acc[7]);
  }
  long long row = (long long)row0 + r;
  if (row < n) {
    float dv = dinv[row];
    __half2 p01 = __floats2half2_rn(acc[0] * dv, acc[1] * dv);
    __half2 p23 = __floats2half2_rn(acc[2] * dv, acc[3] * dv);
    __half2 p45 = __floats2half2_rn(acc[4] * dv, acc[5] * dv);
    __half2 p67 = __floats2half2_rn(acc[6] * dv, acc[7] * dv);
    uint4 u;
    u.x = *reinterpret_cast<unsigned int*>(&p01);
    u.y = *reinterpret_cast<unsigned int*>(&p23);
    u.z = *reinterpret_cast<unsigned int*>(&p45);
    u.w = *reinterpret_cast<unsigned int*>(&p67);
    *reinterpret_cast<uint4*>(T16 + (size_t)row * DD + c0) = u;
  }
}

// ---- dense GEMM: acc = H @ W; epilogue: bias+relu -> fp32, or dinv -> fp16 -
__global__ __launch_bounds__(256) void gemm_kernel(
    const float* __restrict__ H, const float* __restrict__ W,
    const float* __restrict__ bias, const float* __restrict__ dinv,
    float* __restrict__ T32, __half* __restrict__ T16, int n) {
  __shared__ float Ws[64][68];
  __shared__ float Hs[64][68];
  int tid = threadIdx.x;
  int row0 = blockIdx.x * 64;

  for (int i = tid; i < 1024; i += 256) {
    int r = i >> 4, c = (i & 15) << 2;
    *reinterpret_cast<float4*>(&Ws[r][c]) = ((const float4*)W)[i];
    float4 hv = make_float4(0.f, 0.f, 0.f, 0.f);
    if (row0 + r < n)
      hv = *reinterpret_cast<const float4*>(H + (size_t)(row0 + r) * DD + c);
    *reinterpret_cast<float4*>(&Hs[r][c]) = hv;
  }
  __syncthreads();

  int tr = tid >> 4, tc = tid & 15;
  int r0 = tr << 2, c0 = tc << 2;

  float acc[4][4];
#pragma unroll
  for (int i = 0; i < 4; ++i)
#pragma unroll
    for (int j = 0; j < 4; ++j) acc[i][j] = 0.f;

#pragma unroll
  for (int k = 0; k < 64; ++k) {
    float h0 = Hs[r0 + 0][k], h1 = Hs[r0 + 1][k];
    float h2 = Hs[r0 + 2][k], h3 = Hs[r0 + 3][k];
    float4 wv = *reinterpret_cast<const float4*>(&Ws[k][c0]);
    acc[0][0] = fmaf(h0, wv.x, acc[0][0]); acc[0][1] = fmaf(h0, wv.y, acc[0][1]);
    acc[0][2] = fmaf(h0, wv.z, acc[0][2]); acc[0][3] = fmaf(h0, wv.w, acc[0][3]);
    acc[1][0] = fmaf(h1, wv.x, acc[1][0]); acc[1][1] = fmaf(h1, wv.y, acc[1][1]);
    acc[1][2] = fmaf(h1, wv.z, acc[1][2]); acc[1][3] = fmaf(h1, wv.w, acc[1][3]);
    acc[2][0] = fmaf(h2, wv.x, acc[2][0]); acc[2][1] = fmaf(h2, wv.y, acc[2][1]);
    acc[2][2] = fmaf(h2, wv.z, acc[2][2]); acc[2][3] = fmaf(h2, wv.w, acc[2][3]);
    acc[3][0] = fmaf(h3, wv.x, acc[3][0]); acc[3][1] = fmaf(h3, wv.y, acc[3][1]);
    acc[3][2] = fmaf(h3, wv.z, acc[3][2]); acc[3][3] = fmaf(h3, wv.w, acc[3][3]);
  }

  if (T16) {
    // fp16 path: o = dinv[row] * acc
#pragma unroll
    for (int i = 0; i < 4; ++i) {
      long long row = (long long)row0 + r0 + i;
      if (row >= n) break;
      float dv = dinv[row];
      __half2 p01 = __floats2half2_rn(acc[i][0] * dv, acc[i][1] * dv);
      __half2 p23 = __floats2half2_rn(acc[i][2] * dv, acc[i][3] * dv);
      uint2 u;
      u.x = *reinterpret_cast<unsigned int*>(&p01);
      u.y = *reinterpret_cast<unsigned int*>(&p23);
      *reinterpret_cast<uint2*>(T16 + (size_t)row * DD + c0) = u;
    }
  } else {
    // fp32 path: o = relu(acc + bias)
    float4 bv = *reinterpret_cast<const float4*>(bias + c0);
#pragma unroll
    for (int i = 0; i < 4; ++i) {
      long long row = (long long)row0 + r0 + i;
      if (row >= n) break;
      float4 o;
      o.x = fmaxf(acc[i][0] + bv.x, 0.f);
      o.y = fmaxf(acc[i][1] + bv.y, 0.f);
      o.z = fmaxf(acc[i][2] + bv.z, 0.f);
      o.w = fmaxf(acc[i][3] + bv.w, 0.f);
      *reinterpret_cast<float4*>(T32 + (size_t)row * DD + c0) = o;
    }
  }
}

// ---- CSR aggregation: out[d,:] = dinv[d] * sum_{c in N(d)} T16[c,:] + b ---
// one wave per node; lane = (row-group g = lane>>3, dim-slice s = lane&7).
// Wave-cooperative col preload, shfl index distribution, 8-deep masked
// row gathers (all rounds of a 64-batch issued before accumulation).
__device__ __forceinline__ void acc8(float* acc, uint4 u) {
  __half2 h0 = *reinterpret_cast<__half2*>(&u.x);
  __half2 h1 = *reinterpret_cast<__half2*>(&u.y);
  __half2 h2 = *reinterpret_cast<__half2*>(&u.z);
  __half2 h3 = *reinterpret_cast<__half2*>(&u.w);
  float2 f0 = __half22float2(h0);
  float2 f1 = __half22float2(h1);
  float2 f2 = __half22float2(h2);
  float2 f3 = __half22float2(h3);
  acc[0] += f0.x; acc[1] += f0.y;
  acc[2] += f1.x; acc[3] += f1.y;
  acc[4] += f2.x; acc[5] += f2.y;
  acc[6] += f3.x; acc[7] += f3.y;
}

__global__ __launch_bounds__(256) void aggregate_kernel(
    const __half* __restrict__ T, const int* __restrict__ offs,
    const int* __restrict__ col, const float* __restrict__ dinv,
    const float* __restrict__ bias, float* __restrict__ out,
    int n, int relu) {
  int gid = blockIdx.x * blockDim.x + threadIdx.x;
  int wid = gid >> 6;
  if (wid >= n) return;
  int lane = threadIdx.x & 63;
  int g = lane >> 3;          // row group 0..7
  int s = lane & 7;           // dim slice: dims 8s..8s+7
  int j0 = offs[wid], j1 = offs[wid + 1];
  int deg = j1 - j0;
  const __half* Ts = T + s * 8;

  float acc[8];
#pragma unroll
  for (int k = 0; k < 8; ++k) acc[k] = 0.f;

  for (int base = 0; base < deg; base += 64) {
    int idx = base + lane;
    int c_local = (idx < deg) ? col[j0 + idx] : -1;
    int rem = deg - base; if (rem > 64) rem = 64;
    int nr = (rem + 7) >> 3;          // rounds in this batch (wave-uniform)

    int cc[8];
#pragma unroll
    for (int t = 0; t < 8; ++t)
      cc[t] = (t < nr) ? __shfl(c_local, t * 8 + g, 64) : -1;

    uint4 u[8];
#pragma unroll
    for (int t = 0; t < 8; ++t)
      if (cc[t] >= 0)
        u[t] = *reinterpret_cast<const uint4*>(Ts + (size_t)cc[t] * DD);

#pragma unroll
    for (int t = 0; t < 8; ++t)
      if (cc[t] >= 0) acc8(acc, u[t]);
  }

  // reduce over g (lane bits 3,4,5)
#pragma unroll
  for (int m = 8; m <= 32; m <<= 1) {
#pragma unroll
    for (int k = 0; k < 8; ++k)
      acc[k] += __shfl_xor(acc[k], m, 64);
  }

  if (g == 0) {
    float dv = dinv[wid];
    const float4* bp = reinterpret_cast<const float4*>(bias + s * 8);
    float4 b0 = bp[0], b1 = bp[1];
    float4 o0, o1;
    o0.x = fmaf(acc[0], dv, b0.x);
    o0.y = fmaf(acc[1], dv, b0.y);
    o0.z = fmaf(acc[2], dv, b0.z);
    o0.w = fmaf(acc[3], dv, b0.w);
    o1.x = fmaf(acc[4], dv, b1.x);
    o1.y = fmaf(acc[5], dv, b1.y);
    o1.z = fmaf(acc[6], dv, b1.z);
    o1.w = fmaf(acc[7], dv, b1.w);
    if (relu) {
      o0.x = fmaxf(o0.x, 0.f); o0.y = fmaxf(o0.y, 0.f);
      o0.z = fmaxf(o0.z, 0.f); o0.w = fmaxf(o0.w, 0.f);
      o1.x = fmaxf(o1.x, 0.f); o1.y = fmaxf(o1.y, 0.f);
      o1.z = fmaxf(o1.z, 0.f); o1.w = fmaxf(o1.w, 0.f);
    }
    float4* op = reinterpret_cast<float4*>(out + (size_t)wid * DD + s * 8);
    op[0] = o0;
    op[1] = o1;
  }
}

// ---------------------------------------------------------------------------
extern "C" void kernel_launch(void* const* d_in, const int* in_sizes, int n_in,
                              void* d_out, int out_size, void* d_ws, size_t ws_size,
                              hipStream_t stream) {
  const float* x   = (const float*)d_in[0];
  const void*  eix = d_in[1];
  const float* Win = (const float*)d_in[2];
  const float* bin = (const float*)d_in[3];
  const float* W1  = (const float*)d_in[4];
  const float* b1  = (const float*)d_in[5];
  const float* W2  = (const float*)d_in[6];
  const float* b2  = (const float*)d_in[7];
  const float* W3  = (const float*)d_in[8];
  const float* b3  = (const float*)d_in[9];

  int n = in_sizes[0] / DD;
  int E = in_sizes[1] / 2;
  int M = E + n;
  int chunk = (n + NB - 1) / NB;    // local-dst fits 16 bits for n <= 65536

  char* w = (char*)d_ws;
  auto carve = [&](size_t bytes) {
    char* p = w;
    w += (bytes + 255) & ~(size_t)255;
    return p;
  };
  int*          histPB = (int*)carve((size_t)GB * NB * 4);
  int*          offs   = (int*)carve((size_t)(n + 1) * 4);
  float*        dinv   = (float*)carve((size_t)n * 4);
  unsigned int* rec    = (unsigned int*)carve((size_t)E * 4);
  int*          col    = (int*)carve((size_t)M * 4);
  float*        hbuf   = (float*)carve((size_t)n * DD * 4);
  __half*       t16    = (__half*)carve((size_t)n * DD * 2);

  histA_kernel<<<GB, 256, 0, stream>>>(eix, E, chunk, histPB);
  passB2_kernel<<<GB, 256, 0, stream>>>(eix, E, chunk, histPB, rec);
  passC2_kernel<<<NB, 256, 0, stream>>>(rec, histPB, offs, dinv, col, n, E, chunk);

  int tile_grid = (n + 63) / 64;
  int g01_grid  = (n + 31) / 32;
  int agg_grid  = (n * 64 + 255) / 256;

  // fused layer0 + conv1 transform: t16 = dinv * (relu(x@Win+bin) @ W1)
  gemm01_kernel<<<g01_grid, 256, 0, stream>>>(x, Win, bin, W1, dinv, t16, n);
  aggregate_kernel<<<agg_grid, 256, 0, stream>>>(t16, offs, col, dinv, b1, hbuf, n, 1);
  // conv2
  gemm_kernel<<<tile_grid, 256, 0, stream>>>(hbuf, W2, nullptr, dinv, nullptr, t16, n);
  aggregate_kernel<<<agg_grid, 256, 0, stream>>>(t16, offs, col, dinv, b2, hbuf, n, 1);
  // conv3 (no relu, fp32 out)
  gemm_kernel<<<tile_grid, 256, 0, stream>>>(hbuf, W3, nullptr, dinv, nullptr, t16, n);
  aggregate_kernel<<<agg_grid, 256, 0, stream>>>(t16, offs, col, dinv, b3, (float*)d_out, n, 0);
}